// Round 1
// baseline (824.201 us; speedup 1.0000x reference)
//
#include <hip/hip_runtime.h>
#include <math.h>

#define N_NODES 10000
#define N_EDGES 100000
#define HIDDEN  128
#define NHEAD   4
#define CHAN    128
#define IN_DIM  137      // 128 + 6 + 3
#define EDIM    60
#define QKVS    1664     // 512*3 + 128
#define LATD    6
#define DISD    3

// ---------------- Kernel 1: LayerNorm + concat + zero accumulators ----------
__global__ __launch_bounds__(256) void prep_kernel(
    const float* __restrict__ nf, const float* __restrict__ frac,
    const float* __restrict__ lat, const int* __restrict__ n2g,
    const float* __restrict__ gamma, const float* __restrict__ beta,
    float* __restrict__ x, float* __restrict__ sumacc, float* __restrict__ outacc)
{
    int wave = threadIdx.x >> 6;
    int lane = threadIdx.x & 63;
    int n = blockIdx.x * 4 + wave;
    if (n >= N_NODES) return;

    float v0 = nf[n * HIDDEN + lane];
    float v1 = nf[n * HIDDEN + 64 + lane];
    float s  = v0 + v1;
    float sq = v0 * v0 + v1 * v1;
    #pragma unroll
    for (int m = 1; m < 64; m <<= 1) {
        s  += __shfl_xor(s, m);
        sq += __shfl_xor(sq, m);
    }
    float mean = s * (1.0f / 128.0f);
    float var  = sq * (1.0f / 128.0f) - mean * mean;   // biased variance
    float inv  = rsqrtf(var + 1e-5f);

    x[n * IN_DIM + lane]      = (v0 - mean) * inv * gamma[lane]      + beta[lane];
    x[n * IN_DIM + 64 + lane] = (v1 - mean) * inv * gamma[64 + lane] + beta[64 + lane];
    if (lane < LATD) x[n * IN_DIM + HIDDEN + lane]        = lat[n2g[n] * LATD + lane];
    if (lane < DISD) x[n * IN_DIM + HIDDEN + LATD + lane] = frac[n * DISD + lane];

    if (lane < 4) sumacc[n * 4 + lane] = 0.0f;
    #pragma unroll
    for (int k = 0; k < 8; ++k) outacc[n * 512 + lane * 8 + k] = 0.0f;
}

// ---------------- Kernel 2: qkv+skip GEMM  (x[N,137] @ W -> qkvs[N,1664]) ---
// Block: 256 thr, tile = 32 nodes x 128 cols, thread tile 4x4. grid=(13,313)
__global__ __launch_bounds__(256) void qkv_gemm_kernel(
    const float* __restrict__ x,
    const float* __restrict__ Wq, const float* __restrict__ bq,
    const float* __restrict__ Wk, const float* __restrict__ bk,
    const float* __restrict__ Wv, const float* __restrict__ bv,
    const float* __restrict__ Wsk, const float* __restrict__ bsk,
    float* __restrict__ qkvs)
{
    __shared__ float xs[32 * IN_DIM];   // [node][j], row-major
    const int cb = blockIdx.x;          // 0..12 : which 128-col chunk
    const int nb = blockIdx.y;
    const int node0 = nb * 32;

    for (int idx = threadIdx.x; idx < 32 * IN_DIM; idx += 256) {
        int g = node0 * IN_DIM + idx;   // x rows are contiguous -> linear copy
        xs[idx] = (g < N_NODES * IN_DIM) ? x[g] : 0.0f;
    }
    __syncthreads();

    const float* W; const float* bias; int ncols, coloff;
    if (cb < 4)       { W = Wq;  bias = bq;  ncols = 512; coloff = cb * 128; }
    else if (cb < 8)  { W = Wk;  bias = bk;  ncols = 512; coloff = (cb - 4) * 128; }
    else if (cb < 12) { W = Wv;  bias = bv;  ncols = 512; coloff = (cb - 8) * 128; }
    else              { W = Wsk; bias = bsk; ncols = 128; coloff = 0; }

    const int tx = threadIdx.x & 31;    // col / 4
    const int ty = threadIdx.x >> 5;    // node / 4
    const int c0 = coloff + tx * 4;

    float acc[4][4] = {};
    for (int j = 0; j < IN_DIM; ++j) {
        const float4 wv = *reinterpret_cast<const float4*>(&W[(size_t)j * ncols + c0]);
        const float wa[4] = { wv.x, wv.y, wv.z, wv.w };
        #pragma unroll
        for (int i = 0; i < 4; ++i) {
            float xv = xs[(ty * 4 + i) * IN_DIM + j];
            #pragma unroll
            for (int k = 0; k < 4; ++k) acc[i][k] += xv * wa[k];
        }
    }

    const int outcol = cb * 128 + tx * 4;
    const float4 bv4 = *reinterpret_cast<const float4*>(&bias[c0]);
    const float ba[4] = { bv4.x, bv4.y, bv4.z, bv4.w };
    #pragma unroll
    for (int i = 0; i < 4; ++i) {
        int node = node0 + ty * 4 + i;
        if (node < N_NODES) {
            float4 r;
            r.x = acc[i][0] + ba[0]; r.y = acc[i][1] + ba[1];
            r.z = acc[i][2] + ba[2]; r.w = acc[i][3] + ba[3];
            *reinterpret_cast<float4*>(&qkvs[(size_t)node * QKVS + outcol]) = r;
        }
    }
}

// ---------------- Kernel 3: edge pass ---------------------------------------
// grid = (E/32, H). Block computes e-chunk [32 edges x 128 chan (one head)],
// then score, exp-weight (no-max softmax: ratios identical), atomic scatter.
__global__ __launch_bounds__(256) void edge_attn_kernel(
    const float* __restrict__ frac_diff, const int* __restrict__ edge_index,
    const float* __restrict__ We, const float* __restrict__ qkvs,
    float* __restrict__ sumacc, float* __restrict__ outacc)
{
    __shared__ float embs[EDIM * 32];    // [j][edge]
    __shared__ float wel[EDIM * 128];    // [j][c]
    const int e0 = blockIdx.x * 32;
    const int h  = blockIdx.y;
    const float TWO_PI = 6.283185307179586f;

    for (int idx = threadIdx.x; idx < EDIM * 32; idx += 256) {
        int j = idx >> 5, n = idx & 31;
        int jj = (j < 30) ? j : j - 30;
        int sdim = jj / 10;
        int f = jj - sdim * 10;
        float val = frac_diff[(size_t)(e0 + n) * DISD + sdim] * (TWO_PI * (float)f);
        embs[idx] = (j < 30) ? __sinf(val) : __cosf(val);
    }
    for (int idx = threadIdx.x; idx < EDIM * 128; idx += 256) {
        int j = idx >> 7, c = idx & 127;
        wel[idx] = We[j * 512 + h * 128 + c];
    }
    __syncthreads();

    const int tx = threadIdx.x & 31;    // chan / 4
    const int ty = threadIdx.x >> 5;    // edge / 4

    float acc[4][4] = {};               // e fragment: [edge][chan]
    for (int j = 0; j < EDIM; ++j) {
        const float4 wv = *reinterpret_cast<const float4*>(&wel[j * 128 + tx * 4]);
        const float4 ev = *reinterpret_cast<const float4*>(&embs[j * 32 + ty * 4]);
        const float wa[4] = { wv.x, wv.y, wv.z, wv.w };
        const float ea[4] = { ev.x, ev.y, ev.z, ev.w };
        #pragma unroll
        for (int i = 0; i < 4; ++i)
            #pragma unroll
            for (int k = 0; k < 4; ++k) acc[i][k] += ea[i] * wa[k];
    }

    const float scale = 0.08838834764831845f;  // 1/sqrt(128)
    #pragma unroll
    for (int i = 0; i < 4; ++i) {
        const int e   = e0 + ty * 4 + i;
        const int src = edge_index[e];
        const int dst = edge_index[N_EDGES + e];
        const float4 q4 = *reinterpret_cast<const float4*>(
            &qkvs[(size_t)dst * QKVS + h * 128 + tx * 4]);
        const float4 k4 = *reinterpret_cast<const float4*>(
            &qkvs[(size_t)src * QKVS + 512 + h * 128 + tx * 4]);
        float partial = q4.x * (k4.x + acc[i][0]) + q4.y * (k4.y + acc[i][1])
                      + q4.z * (k4.z + acc[i][2]) + q4.w * (k4.w + acc[i][3]);
        #pragma unroll
        for (int m = 1; m < 32; m <<= 1) partial += __shfl_xor(partial, m);
        const float w = __expf(partial * scale);
        if (tx == 0) atomicAdd(&sumacc[dst * 4 + h], w);
        const float4 v4 = *reinterpret_cast<const float4*>(
            &qkvs[(size_t)src * QKVS + 1024 + h * 128 + tx * 4]);
        float* op = &outacc[(size_t)dst * 512 + h * 128 + tx * 4];
        atomicAdd(op + 0, w * (v4.x + acc[i][0]));
        atomicAdd(op + 1, w * (v4.y + acc[i][1]));
        atomicAdd(op + 2, w * (v4.z + acc[i][2]));
        atomicAdd(op + 3, w * (v4.w + acc[i][3]));
    }
}

// ---------------- Kernel 4: finalize ----------------------------------------
__global__ __launch_bounds__(256) void finalize_kernel(
    const float* __restrict__ nf, const float* __restrict__ qkvs,
    const float* __restrict__ sumacc, const float* __restrict__ outacc,
    float* __restrict__ out)
{
    int idx = blockIdx.x * 256 + threadIdx.x;
    if (idx >= N_NODES * CHAN) return;
    int n = idx >> 7, c = idx & 127;
    float acc = 0.0f;
    #pragma unroll
    for (int h = 0; h < NHEAD; ++h) {
        float s = sumacc[n * 4 + h];
        acc += outacc[(size_t)n * 512 + h * 128 + c] / (s + 1e-16f);
    }
    acc *= 0.25f;                                   // head mean
    float z = acc + qkvs[(size_t)n * QKVS + 1536 + c];  // + skip
    float si = z / (1.0f + __expf(-z));             // silu
    out[idx] = nf[idx] + si;                        // residual
}

// ---------------- launcher ---------------------------------------------------
extern "C" void kernel_launch(void* const* d_in, const int* in_sizes, int n_in,
                              void* d_out, int out_size, void* d_ws, size_t ws_size,
                              hipStream_t stream)
{
    const float* nf    = (const float*)d_in[0];
    const float* frac  = (const float*)d_in[1];
    const float* lat   = (const float*)d_in[2];
    const int*   eidx  = (const int*)  d_in[3];
    const int*   n2g   = (const int*)  d_in[4];
    const float* fdiff = (const float*)d_in[5];
    const float* gamma = (const float*)d_in[6];
    const float* beta  = (const float*)d_in[7];
    const float* Wq    = (const float*)d_in[8];
    const float* bq    = (const float*)d_in[9];
    const float* Wk    = (const float*)d_in[10];
    const float* bk    = (const float*)d_in[11];
    const float* Wv    = (const float*)d_in[12];
    const float* bv    = (const float*)d_in[13];
    const float* We    = (const float*)d_in[14];
    const float* Wsk   = (const float*)d_in[15];
    const float* bsk   = (const float*)d_in[16];
    float* out = (float*)d_out;

    float* x      = (float*)d_ws;                          // N*137
    float* qkvs   = x + (size_t)N_NODES * IN_DIM;          // N*1664
    float* sumacc = qkvs + (size_t)N_NODES * QKVS;         // N*4
    float* outacc = sumacc + (size_t)N_NODES * 4;          // N*512

    prep_kernel<<<(N_NODES + 3) / 4, 256, 0, stream>>>(
        nf, frac, lat, n2g, gamma, beta, x, sumacc, outacc);

    dim3 ggrid(13, (N_NODES + 31) / 32);
    qkv_gemm_kernel<<<ggrid, 256, 0, stream>>>(
        x, Wq, bq, Wk, bk, Wv, bv, Wsk, bsk, qkvs);

    dim3 egrid(N_EDGES / 32, NHEAD);
    edge_attn_kernel<<<egrid, 256, 0, stream>>>(
        fdiff, eidx, We, qkvs, sumacc, outacc);

    finalize_kernel<<<(N_NODES * CHAN + 255) / 256, 256, 0, stream>>>(
        nf, qkvs, sumacc, outacc, out);
}

// Round 2
// 265.381 us; speedup vs baseline: 3.1057x; 3.1057x over previous
//
#include <hip/hip_runtime.h>
#include <math.h>

#define N_NODES 10000
#define N_EDGES 100000
#define HIDDEN  128
#define NHEAD   4
#define CHAN    128
#define IN_DIM  137      // 128 + 6 + 3
#define EDIM    60
#define QKVS2   1904     // 512*3 + 128 + 240 (qe)
#define LATD    6
#define DISD    3

// ---------------- Kernel 0a: zero histogram ---------------------------------
__global__ __launch_bounds__(256) void zero_hist_kernel(int* __restrict__ hist)
{
    int i = blockIdx.x * 256 + threadIdx.x;
    if (i < N_NODES) hist[i] = 0;
}

// ---------------- Kernel 0b: histogram of dst -------------------------------
__global__ __launch_bounds__(256) void hist_kernel(
    const int* __restrict__ eidx, int* __restrict__ hist)
{
    int e = blockIdx.x * 256 + threadIdx.x;
    if (e < N_EDGES) atomicAdd(&hist[eidx[N_EDGES + e]], 1);
}

// ---------------- Kernel 0c: exclusive scan (single block) ------------------
__global__ __launch_bounds__(1024) void scan_kernel(
    const int* __restrict__ hist, int* __restrict__ offsets, int* __restrict__ cursor)
{
    __shared__ int part[1024];
    const int t = threadIdx.x;
    const int base = t * 10;
    int loc[10];
    int s = 0;
    #pragma unroll
    for (int i = 0; i < 10; ++i) {
        int v = (base + i < N_NODES) ? hist[base + i] : 0;
        loc[i] = s; s += v;
    }
    part[t] = s;
    __syncthreads();
    for (int off = 1; off < 1024; off <<= 1) {
        int v = (t >= off) ? part[t - off] : 0;
        __syncthreads();
        part[t] += v;
        __syncthreads();
    }
    int pre = (t > 0) ? part[t - 1] : 0;
    #pragma unroll
    for (int i = 0; i < 10; ++i)
        if (base + i < N_NODES) {
            offsets[base + i] = pre + loc[i];
            cursor[base + i]  = pre + loc[i];
        }
    if (t == 1023) offsets[N_NODES] = part[1023];
}

// ---------------- Kernel 0d: scatter edges into dst-sorted order ------------
__global__ __launch_bounds__(256) void scatter_kernel(
    const int* __restrict__ eidx, const float* __restrict__ fdiff,
    int* __restrict__ cursor, int* __restrict__ sorted_src,
    float* __restrict__ sorted_fd)
{
    int e = blockIdx.x * 256 + threadIdx.x;
    if (e >= N_EDGES) return;
    int src = eidx[e];
    int dst = eidx[N_EDGES + e];
    int pos = atomicAdd(&cursor[dst], 1);
    sorted_src[pos] = src;
    sorted_fd[pos * 3 + 0] = fdiff[e * 3 + 0];
    sorted_fd[pos * 3 + 1] = fdiff[e * 3 + 1];
    sorted_fd[pos * 3 + 2] = fdiff[e * 3 + 2];
}

// ---------------- Kernel 1: LayerNorm + concat -------------------------------
__global__ __launch_bounds__(256) void prep_kernel(
    const float* __restrict__ nf, const float* __restrict__ frac,
    const float* __restrict__ lat, const int* __restrict__ n2g,
    const float* __restrict__ gamma, const float* __restrict__ beta,
    float* __restrict__ x)
{
    int wave = threadIdx.x >> 6;
    int lane = threadIdx.x & 63;
    int n = blockIdx.x * 4 + wave;
    if (n >= N_NODES) return;

    float v0 = nf[n * HIDDEN + lane];
    float v1 = nf[n * HIDDEN + 64 + lane];
    float s  = v0 + v1;
    float sq = v0 * v0 + v1 * v1;
    #pragma unroll
    for (int m = 1; m < 64; m <<= 1) {
        s  += __shfl_xor(s, m);
        sq += __shfl_xor(sq, m);
    }
    float mean = s * (1.0f / 128.0f);
    float var  = sq * (1.0f / 128.0f) - mean * mean;   // biased variance
    float inv  = rsqrtf(var + 1e-5f);

    x[n * IN_DIM + lane]      = (v0 - mean) * inv * gamma[lane]      + beta[lane];
    x[n * IN_DIM + 64 + lane] = (v1 - mean) * inv * gamma[64 + lane] + beta[64 + lane];
    if (lane < LATD) x[n * IN_DIM + HIDDEN + lane]        = lat[n2g[n] * LATD + lane];
    if (lane < DISD) x[n * IN_DIM + HIDDEN + LATD + lane] = frac[n * DISD + lane];
}

// ---------------- Kernel 2a: fused weight Wqe = Wq (x) We^T per head ---------
// Wqe[i][h*60+j] = sum_c Wq[i][h*128+c] * We[j][h*128+c]; row 137 = bias (bq).
__global__ __launch_bounds__(256) void wqe_kernel(
    const float* __restrict__ Wq, const float* __restrict__ bq,
    const float* __restrict__ We, float* __restrict__ Wqe)
{
    int idx = blockIdx.x * 256 + threadIdx.x;
    if (idx >= 138 * 240) return;
    int i  = idx / 240;
    int hj = idx % 240;
    int h  = hj / 60;
    int j  = hj % 60;
    const float* arow = (i < IN_DIM) ? &Wq[(size_t)i * 512] : bq;
    const float* wrow = &We[(size_t)j * 512];
    float s = 0.0f;
    #pragma unroll 4
    for (int c = 0; c < 128; ++c) s += arow[h * 128 + c] * wrow[h * 128 + c];
    Wqe[idx] = s;
}

// ---------------- Kernel 2b: big GEMM  x[N,137] @ {Wq,Wk,Wv,Wskip,Wqe} -------
// Block: 256 thr, tile = 32 nodes x 128 cols, thread tile 4x4. grid=(15,313)
__global__ __launch_bounds__(256) void qkv_gemm_kernel(
    const float* __restrict__ x,
    const float* __restrict__ Wq, const float* __restrict__ bq,
    const float* __restrict__ Wk, const float* __restrict__ bk,
    const float* __restrict__ Wv, const float* __restrict__ bv,
    const float* __restrict__ Wsk, const float* __restrict__ bsk,
    const float* __restrict__ Wqe,
    float* __restrict__ qkvs)
{
    __shared__ float xs[32 * IN_DIM];   // [node][j], row-major
    const int cb = blockIdx.x;          // 0..14 : which 128-col chunk
    const int nb = blockIdx.y;
    const int node0 = nb * 32;

    for (int idx = threadIdx.x; idx < 32 * IN_DIM; idx += 256) {
        int g = node0 * IN_DIM + idx;   // x rows contiguous -> linear copy
        xs[idx] = (g < N_NODES * IN_DIM) ? x[g] : 0.0f;
    }
    __syncthreads();

    const float* W; const float* bias; int ncols, coloff;
    if (cb < 4)       { W = Wq;  bias = bq;  ncols = 512; coloff = cb * 128; }
    else if (cb < 8)  { W = Wk;  bias = bk;  ncols = 512; coloff = (cb - 4) * 128; }
    else if (cb < 12) { W = Wv;  bias = bv;  ncols = 512; coloff = (cb - 8) * 128; }
    else if (cb < 13) { W = Wsk; bias = bsk; ncols = 128; coloff = 0; }
    else              { W = Wqe; bias = &Wqe[137 * 240]; ncols = 240; coloff = (cb - 13) * 128; }

    const int tx = threadIdx.x & 31;    // col / 4
    const int ty = threadIdx.x >> 5;    // node / 4
    const int c0 = coloff + tx * 4;
    const bool cvalid = (c0 + 4 <= ncols);
    const int cload = cvalid ? c0 : (ncols - 4);

    float acc[4][4] = {};
    for (int j = 0; j < IN_DIM; ++j) {
        const float4 wv = *reinterpret_cast<const float4*>(&W[(size_t)j * ncols + cload]);
        const float wa[4] = { wv.x, wv.y, wv.z, wv.w };
        #pragma unroll
        for (int i = 0; i < 4; ++i) {
            float xv = xs[(ty * 4 + i) * IN_DIM + j];
            #pragma unroll
            for (int k = 0; k < 4; ++k) acc[i][k] += xv * wa[k];
        }
    }

    const int outcol = cb * 128 + tx * 4;
    const float4 bv4 = *reinterpret_cast<const float4*>(&bias[cload]);
    const float ba[4] = { bv4.x, bv4.y, bv4.z, bv4.w };
    #pragma unroll
    for (int i = 0; i < 4; ++i) {
        int node = node0 + ty * 4 + i;
        if (node < N_NODES && cvalid) {
            float4 r;
            r.x = acc[i][0] + ba[0]; r.y = acc[i][1] + ba[1];
            r.z = acc[i][2] + ba[2]; r.w = acc[i][3] + ba[3];
            *reinterpret_cast<float4*>(&qkvs[(size_t)node * QKVS2 + outcol]) = r;
        }
    }
}

// ---------------- Kernel 3: per-node gather (no atomics) ---------------------
// Block = 1 node, 4 waves = 4 heads. Wave walks the node's dst-sorted edges:
//   score = (q.k + qe.emb)/sqrt(C); w = exp(score)  [no-max softmax, same ratios]
//   acc += w * v[src];  aggemb += w * emb;  sumw += w
// Epilogue: acc += aggemb @ We_head; out = nf + silu(mean_h(acc/sumw) + skip)
__global__ __launch_bounds__(256) void gather_kernel(
    const float* __restrict__ qkvs, const float* __restrict__ We,
    const int* __restrict__ offsets, const int* __restrict__ sorted_src,
    const float* __restrict__ sorted_fd, const float* __restrict__ nf,
    float* __restrict__ out)
{
    __shared__ float headout[NHEAD][CHAN];
    const int n = blockIdx.x;
    const int h = threadIdx.x >> 6;
    const int l = threadIdx.x & 63;
    const float TWO_PI = 6.283185307179586f;
    const float scale  = 0.08838834764831845f;   // 1/sqrt(128)

    const size_t nrow = (size_t)n * QKVS2;
    const float2 q2 = *reinterpret_cast<const float2*>(&qkvs[nrow + h * 128 + 2 * l]);
    const float qe_l = (l < 60) ? qkvs[nrow + 1664 + h * 60 + l] : 0.0f;

    // sinusoid coefficients for this lane (lanes 0..29 sin, 30..59 cos)
    const int  jj    = (l < 30) ? l : l - 30;
    const int  sdim  = (l < 60) ? (jj / 10) : 0;
    const float fcoef = (l < 60) ? (TWO_PI * (float)(jj % 10)) : 0.0f;

    float accx = 0.f, accy = 0.f, aggemb = 0.f, sumw = 0.f;
    const int e0 = offsets[n], e1 = offsets[n + 1];
    for (int e = e0; e < e1; ++e) {
        const int src = sorted_src[e];
        const float val = sorted_fd[e * 3 + sdim] * fcoef;
        const float emb = (l < 30) ? __sinf(val) : __cosf(val);
        const size_t srow = (size_t)src * QKVS2;
        const float2 k2 = *reinterpret_cast<const float2*>(&qkvs[srow + 512 + h * 128 + 2 * l]);
        float partial = q2.x * k2.x + q2.y * k2.y + ((l < 60) ? emb * qe_l : 0.0f);
        #pragma unroll
        for (int m = 1; m < 64; m <<= 1) partial += __shfl_xor(partial, m);
        const float w = __expf(partial * scale);
        sumw += w;
        const float2 v2 = *reinterpret_cast<const float2*>(&qkvs[srow + 1024 + h * 128 + 2 * l]);
        accx += w * v2.x; accy += w * v2.y;
        if (l < 60) aggemb += w * emb;
    }

    // e-contribution: (sum_e w*emb) @ We_head
    for (int j = 0; j < 60; ++j) {
        const float a = __shfl(aggemb, j);
        const float2 we2 = *reinterpret_cast<const float2*>(&We[j * 512 + h * 128 + 2 * l]);
        accx += a * we2.x; accy += a * we2.y;
    }

    const float inv = 1.0f / (sumw + 1e-16f);
    headout[h][2 * l]     = accx * inv;
    headout[h][2 * l + 1] = accy * inv;
    __syncthreads();

    if (threadIdx.x < CHAN) {
        const int c = threadIdx.x;
        float z = 0.25f * (headout[0][c] + headout[1][c] + headout[2][c] + headout[3][c])
                + qkvs[nrow + 1536 + c];
        float si = z / (1.0f + __expf(-z));
        out[n * CHAN + c] = nf[n * CHAN + c] + si;
    }
}

// ---------------- launcher ---------------------------------------------------
extern "C" void kernel_launch(void* const* d_in, const int* in_sizes, int n_in,
                              void* d_out, int out_size, void* d_ws, size_t ws_size,
                              hipStream_t stream)
{
    const float* nf    = (const float*)d_in[0];
    const float* frac  = (const float*)d_in[1];
    const float* lat   = (const float*)d_in[2];
    const int*   eidx  = (const int*)  d_in[3];
    const int*   n2g   = (const int*)  d_in[4];
    const float* fdiff = (const float*)d_in[5];
    const float* gamma = (const float*)d_in[6];
    const float* beta  = (const float*)d_in[7];
    const float* Wq    = (const float*)d_in[8];
    const float* bq    = (const float*)d_in[9];
    const float* Wk    = (const float*)d_in[10];
    const float* bk    = (const float*)d_in[11];
    const float* Wv    = (const float*)d_in[12];
    const float* bv    = (const float*)d_in[13];
    const float* We    = (const float*)d_in[14];
    const float* Wsk   = (const float*)d_in[15];
    const float* bsk   = (const float*)d_in[16];
    float* out = (float*)d_out;

    // workspace layout (floats, then ints)
    float* x         = (float*)d_ws;                         // N*137
    float* qkvs      = x + (size_t)N_NODES * IN_DIM;         // N*1904
    float* Wqe       = qkvs + (size_t)N_NODES * QKVS2;       // 138*240
    float* sorted_fd = Wqe + 138 * 240;                      // E*3
    int*   hist      = (int*)(sorted_fd + (size_t)N_EDGES * 3); // N
    int*   offsets   = hist + N_NODES;                       // N+1
    int*   cursor    = offsets + N_NODES + 1;                // N
    int*   sorted_src= cursor + N_NODES;                     // E

    zero_hist_kernel<<<(N_NODES + 255) / 256, 256, 0, stream>>>(hist);
    hist_kernel<<<(N_EDGES + 255) / 256, 256, 0, stream>>>(eidx, hist);
    scan_kernel<<<1, 1024, 0, stream>>>(hist, offsets, cursor);
    scatter_kernel<<<(N_EDGES + 255) / 256, 256, 0, stream>>>(
        eidx, fdiff, cursor, sorted_src, sorted_fd);

    prep_kernel<<<(N_NODES + 3) / 4, 256, 0, stream>>>(
        nf, frac, lat, n2g, gamma, beta, x);

    wqe_kernel<<<(138 * 240 + 255) / 256, 256, 0, stream>>>(Wq, bq, We, Wqe);

    dim3 ggrid(15, (N_NODES + 31) / 32);
    qkv_gemm_kernel<<<ggrid, 256, 0, stream>>>(
        x, Wq, bq, Wk, bk, Wv, bv, Wsk, bsk, Wqe, qkvs);

    gather_kernel<<<N_NODES, 256, 0, stream>>>(
        qkvs, We, offsets, sorted_src, sorted_fd, nf, out);
}

// Round 3
// 208.415 us; speedup vs baseline: 3.9546x; 1.2733x over previous
//
#include <hip/hip_runtime.h>
#include <math.h>

#define N_NODES 10000
#define N_EDGES 100000
#define HIDDEN  128
#define NHEAD   4
#define CHAN    128
#define IN_DIM  137      // 128 + 6 + 3
#define KPAD    160      // padded K for MFMA
#define NCOLS   1904     // 512*3 + 128 + 240
#define NPAD    1920     // padded to 15*128
#define LATD    6
#define DISD    3

typedef __attribute__((ext_vector_type(8))) short short8v;
typedef __attribute__((ext_vector_type(4))) float float4v;

__device__ inline unsigned short f2bf(float f) {
    unsigned u = __float_as_uint(f);
    unsigned r = 0x7fffu + ((u >> 16) & 1u);
    return (unsigned short)((u + r) >> 16);
}
__device__ inline float2 bf2f2(unsigned u) {
    float2 r;
    r.x = __uint_as_float(u << 16);
    r.y = __uint_as_float(u & 0xffff0000u);
    return r;
}

// ---------------- Kernel 0a: zero histogram ---------------------------------
__global__ __launch_bounds__(256) void zero_hist_kernel(int* __restrict__ hist)
{
    int i = blockIdx.x * 256 + threadIdx.x;
    if (i < N_NODES) hist[i] = 0;
}

// ---------------- Kernel 0b: histogram of dst -------------------------------
__global__ __launch_bounds__(256) void hist_kernel(
    const int* __restrict__ eidx, int* __restrict__ hist)
{
    int e = blockIdx.x * 256 + threadIdx.x;
    if (e < N_EDGES) atomicAdd(&hist[eidx[N_EDGES + e]], 1);
}

// ---------------- Kernel 0c: exclusive scan (single block) ------------------
__global__ __launch_bounds__(1024) void scan_kernel(
    const int* __restrict__ hist, int* __restrict__ offsets, int* __restrict__ cursor)
{
    __shared__ int part[1024];
    const int t = threadIdx.x;
    const int base = t * 10;
    int loc[10];
    int s = 0;
    #pragma unroll
    for (int i = 0; i < 10; ++i) {
        int v = (base + i < N_NODES) ? hist[base + i] : 0;
        loc[i] = s; s += v;
    }
    part[t] = s;
    __syncthreads();
    for (int off = 1; off < 1024; off <<= 1) {
        int v = (t >= off) ? part[t - off] : 0;
        __syncthreads();
        part[t] += v;
        __syncthreads();
    }
    int pre = (t > 0) ? part[t - 1] : 0;
    #pragma unroll
    for (int i = 0; i < 10; ++i)
        if (base + i < N_NODES) {
            offsets[base + i] = pre + loc[i];
            cursor[base + i]  = pre + loc[i];
        }
    if (t == 1023) offsets[N_NODES] = part[1023];
}

// ---------------- Kernel 0d: scatter edges into dst-sorted order ------------
__global__ __launch_bounds__(256) void scatter_kernel(
    const int* __restrict__ eidx, const float* __restrict__ fdiff,
    int* __restrict__ cursor, int* __restrict__ sorted_src,
    float* __restrict__ sorted_fd)
{
    int e = blockIdx.x * 256 + threadIdx.x;
    if (e >= N_EDGES) return;
    int src = eidx[e];
    int dst = eidx[N_EDGES + e];
    int pos = atomicAdd(&cursor[dst], 1);
    sorted_src[pos] = src;
    sorted_fd[pos * 3 + 0] = fdiff[e * 3 + 0];
    sorted_fd[pos * 3 + 1] = fdiff[e * 3 + 1];
    sorted_fd[pos * 3 + 2] = fdiff[e * 3 + 2];
}

// ---------------- Kernel 1: LayerNorm + concat -> bf16 x [N][160] ------------
__global__ __launch_bounds__(256) void prep_kernel(
    const float* __restrict__ nf, const float* __restrict__ frac,
    const float* __restrict__ lat, const int* __restrict__ n2g,
    const float* __restrict__ gamma, const float* __restrict__ beta,
    unsigned short* __restrict__ xb)
{
    int wave = threadIdx.x >> 6;
    int lane = threadIdx.x & 63;
    int n = blockIdx.x * 4 + wave;
    if (n >= N_NODES) return;

    float v0 = nf[n * HIDDEN + lane];
    float v1 = nf[n * HIDDEN + 64 + lane];
    float s  = v0 + v1;
    float sq = v0 * v0 + v1 * v1;
    #pragma unroll
    for (int m = 1; m < 64; m <<= 1) {
        s  += __shfl_xor(s, m);
        sq += __shfl_xor(sq, m);
    }
    float mean = s * (1.0f / 128.0f);
    float var  = sq * (1.0f / 128.0f) - mean * mean;   // biased variance
    float inv  = rsqrtf(var + 1e-5f);

    xb[n * KPAD + lane]      = f2bf((v0 - mean) * inv * gamma[lane]      + beta[lane]);
    xb[n * KPAD + 64 + lane] = f2bf((v1 - mean) * inv * gamma[64 + lane] + beta[64 + lane]);
    if (lane < LATD) xb[n * KPAD + HIDDEN + lane]        = f2bf(lat[n2g[n] * LATD + lane]);
    if (lane < DISD) xb[n * KPAD + HIDDEN + LATD + lane] = f2bf(frac[n * DISD + lane]);
    if (lane >= 41)  xb[n * KPAD + 96 + lane] = 0;      // cols 137..159 zero-pad
}

// ---------------- Kernel 2a: WallT[n][k] bf16 for q,k,v,skip + biases --------
__global__ __launch_bounds__(256) void wall_kernel(
    const float* __restrict__ Wq, const float* __restrict__ bq,
    const float* __restrict__ Wk, const float* __restrict__ bk,
    const float* __restrict__ Wv, const float* __restrict__ bv,
    const float* __restrict__ Wsk, const float* __restrict__ bsk,
    unsigned short* __restrict__ wallT, float* __restrict__ bias_all)
{
    int idx = blockIdx.x * 256 + threadIdx.x;
    if (idx >= 1664 * KPAD) return;
    int n = idx / KPAD, k = idx % KPAD;
    float val = 0.0f;
    if (k < IN_DIM) {
        if (n < 512)        val = Wq[(size_t)k * 512 + n];
        else if (n < 1024)  val = Wk[(size_t)k * 512 + (n - 512)];
        else if (n < 1536)  val = Wv[(size_t)k * 512 + (n - 1024)];
        else                val = Wsk[(size_t)k * 128 + (n - 1536)];
    }
    wallT[idx] = f2bf(val);
    if (k == 0) {
        float b;
        if (n < 512)        b = bq[n];
        else if (n < 1024)  b = bk[n - 512];
        else if (n < 1536)  b = bv[n - 1024];
        else                b = bsk[n - 1536];
        bias_all[n] = b;
    }
}

// ---------------- Kernel 2b: fused Wqe = Wq (x) We^T per head -> WallT -------
__global__ __launch_bounds__(256) void wqe_kernel(
    const float* __restrict__ Wq, const float* __restrict__ bq,
    const float* __restrict__ We,
    unsigned short* __restrict__ wallT, float* __restrict__ bias_all)
{
    int idx = blockIdx.x * 256 + threadIdx.x;
    if (idx >= 240 * KPAD) return;
    int hj = idx / KPAD, k = idx % KPAD;
    int h = hj / 60, j = hj % 60;
    float s = 0.0f;
    if (k < IN_DIM) {
        #pragma unroll 4
        for (int c = 0; c < 128; ++c)
            s += Wq[(size_t)k * 512 + h * 128 + c] * We[(size_t)j * 512 + h * 128 + c];
    }
    wallT[(size_t)(1664 + hj) * KPAD + k] = f2bf(s);
    if (k == KPAD - 1) {
        float b = 0.0f;
        #pragma unroll 4
        for (int c = 0; c < 128; ++c)
            b += bq[h * 128 + c] * We[(size_t)j * 512 + h * 128 + c];
        bias_all[1664 + hj] = b;
    }
}

// ---------------- Kernel 3: MFMA GEMM xb[N,160] @ WallT^T -> qsq f32, kv bf16
// Block 256 thr = 4 waves (2x2), tile 64 rows x 128 cols, full K in LDS.
__global__ __launch_bounds__(256) void mfma_gemm_kernel(
    const unsigned short* __restrict__ xb, const unsigned short* __restrict__ wallT,
    const float* __restrict__ bias_all,
    float* __restrict__ qsq, unsigned short* __restrict__ kv)
{
    __shared__ __align__(16) unsigned short Alds[64 * 168];
    __shared__ __align__(16) unsigned short Blds[128 * 168];
    const int row0 = blockIdx.y * 64;
    const int col0 = blockIdx.x * 128;
    const int tid  = threadIdx.x;

    for (int i = tid; i < 64 * 20; i += 256) {       // A: 64 rows x 160 bf16
        int r = i / 20, c8 = (i % 20) * 8;
        uint4 v = make_uint4(0u, 0u, 0u, 0u);
        if (row0 + r < N_NODES)
            v = *reinterpret_cast<const uint4*>(&xb[(size_t)(row0 + r) * KPAD + c8]);
        *reinterpret_cast<uint4*>(&Alds[r * 168 + c8]) = v;
    }
    for (int i = tid; i < 128 * 20; i += 256) {      // B: 128 cols x 160 bf16
        int n = i / 20, c8 = (i % 20) * 8;
        uint4 v = *reinterpret_cast<const uint4*>(&wallT[(size_t)(col0 + n) * KPAD + c8]);
        *reinterpret_cast<uint4*>(&Blds[n * 168 + c8]) = v;
    }
    __syncthreads();

    const int l   = tid & 63;
    const int wid = tid >> 6;
    const int wr  = (wid >> 1) * 32;
    const int wc  = (wid & 1) * 64;
    const int lr  = l & 15;
    const int lk  = (l >> 4) * 8;

    float4v acc[2][4];
    #pragma unroll
    for (int tr = 0; tr < 2; ++tr)
        #pragma unroll
        for (int tc = 0; tc < 4; ++tc)
            acc[tr][tc] = (float4v){0.0f, 0.0f, 0.0f, 0.0f};

    #pragma unroll
    for (int ks = 0; ks < 5; ++ks) {
        short8v a[2], b[4];
        #pragma unroll
        for (int t = 0; t < 2; ++t)
            a[t] = *reinterpret_cast<const short8v*>(&Alds[(wr + t * 16 + lr) * 168 + ks * 32 + lk]);
        #pragma unroll
        for (int t = 0; t < 4; ++t)
            b[t] = *reinterpret_cast<const short8v*>(&Blds[(wc + t * 16 + lr) * 168 + ks * 32 + lk]);
        #pragma unroll
        for (int tr = 0; tr < 2; ++tr)
            #pragma unroll
            for (int tc = 0; tc < 4; ++tc)
                acc[tr][tc] = __builtin_amdgcn_mfma_f32_16x16x32_bf16(a[tr], b[tc], acc[tr][tc], 0, 0, 0);
    }

    #pragma unroll
    for (int tr = 0; tr < 2; ++tr) {
        #pragma unroll
        for (int tc = 0; tc < 4; ++tc) {
            const int col  = col0 + wc + tc * 16 + lr;
            const float bias = bias_all[col];
            #pragma unroll
            for (int j = 0; j < 4; ++j) {
                const int row = row0 + wr + tr * 16 + (l >> 4) * 4 + j;
                if (row < N_NODES) {
                    float val = acc[tr][tc][j] + bias;
                    if (col < 512)
                        qsq[(size_t)row * 880 + col] = val;
                    else if (col < 1536)
                        kv[(size_t)row * 1024 + (col - 512)] = f2bf(val);
                    else if (col < NCOLS)
                        qsq[(size_t)row * 880 + (col - 1024)] = val;
                }
            }
        }
    }
}

// ---------------- Kernel 4: per-node gather (no atomics, bf16 kv) ------------
__global__ __launch_bounds__(256) void gather_kernel(
    const float* __restrict__ qsq, const unsigned short* __restrict__ kv,
    const float* __restrict__ We,
    const int* __restrict__ offsets, const int* __restrict__ sorted_src,
    const float* __restrict__ sorted_fd, const float* __restrict__ nf,
    float* __restrict__ out)
{
    __shared__ float headout[NHEAD][CHAN];
    const int n = blockIdx.x;
    const int h = threadIdx.x >> 6;
    const int l = threadIdx.x & 63;
    const float TWO_PI = 6.283185307179586f;
    const float scale  = 0.08838834764831845f;   // 1/sqrt(128)

    const size_t nrow = (size_t)n * 880;
    const float2 q2  = *reinterpret_cast<const float2*>(&qsq[nrow + h * 128 + 2 * l]);
    const float qe_l = (l < 60) ? qsq[nrow + 640 + h * 60 + l] : 0.0f;

    const int  jj    = (l < 30) ? l : l - 30;
    const int  sdim  = (l < 60) ? (jj / 10) : 0;
    const float fcoef = (l < 60) ? (TWO_PI * (float)(jj % 10)) : 0.0f;

    float accx = 0.f, accy = 0.f, aggemb = 0.f, sumw = 0.f;
    const int e0 = offsets[n], e1 = offsets[n + 1];
    for (int e = e0; e < e1; e += 2) {
        const bool h2 = (e + 1 < e1);
        const int eB   = h2 ? e + 1 : e;
        const int srcA = sorted_src[e];
        const int srcB = sorted_src[eB];
        const float fdA = (l < 60) ? sorted_fd[e * 3 + sdim] * fcoef : 0.0f;
        const float fdB = (l < 60) ? sorted_fd[eB * 3 + sdim] * fcoef : 0.0f;
        // issue all 4 gathers before compute
        const unsigned kAu = *reinterpret_cast<const unsigned*>(&kv[(size_t)srcA * 1024 + h * 128 + 2 * l]);
        const unsigned kBu = *reinterpret_cast<const unsigned*>(&kv[(size_t)srcB * 1024 + h * 128 + 2 * l]);
        const unsigned vAu = *reinterpret_cast<const unsigned*>(&kv[(size_t)srcA * 1024 + 512 + h * 128 + 2 * l]);
        const unsigned vBu = *reinterpret_cast<const unsigned*>(&kv[(size_t)srcB * 1024 + 512 + h * 128 + 2 * l]);

        const float embA = (l < 30) ? __sinf(fdA) : __cosf(fdA);
        const float embB = (l < 30) ? __sinf(fdB) : __cosf(fdB);

        const float2 kA = bf2f2(kAu);
        const float2 kB = bf2f2(kBu);
        float pA = q2.x * kA.x + q2.y * kA.y + ((l < 60) ? embA * qe_l : 0.0f);
        float pB = q2.x * kB.x + q2.y * kB.y + ((l < 60) ? embB * qe_l : 0.0f);
        #pragma unroll
        for (int m = 1; m < 64; m <<= 1) {
            pA += __shfl_xor(pA, m);
            pB += __shfl_xor(pB, m);
        }
        const float wA = __expf(pA * scale);
        const float wB = h2 ? __expf(pB * scale) : 0.0f;
        sumw += wA + wB;
        const float2 vA = bf2f2(vAu);
        const float2 vB = bf2f2(vBu);
        accx += wA * vA.x + wB * vB.x;
        accy += wA * vA.y + wB * vB.y;
        aggemb += wA * embA + wB * embB;
    }

    // e-contribution: (sum_e w*emb) @ We_head
    for (int j = 0; j < 60; ++j) {
        const float a = __shfl(aggemb, j);
        const float2 we2 = *reinterpret_cast<const float2*>(&We[j * 512 + h * 128 + 2 * l]);
        accx += a * we2.x; accy += a * we2.y;
    }

    const float inv = 1.0f / (sumw + 1e-16f);
    headout[h][2 * l]     = accx * inv;
    headout[h][2 * l + 1] = accy * inv;
    __syncthreads();

    if (threadIdx.x < CHAN) {
        const int c = threadIdx.x;
        float z = 0.25f * (headout[0][c] + headout[1][c] + headout[2][c] + headout[3][c])
                + qsq[nrow + 512 + c];                       // skip
        float si = z / (1.0f + __expf(-z));
        out[n * CHAN + c] = nf[n * CHAN + c] + si;
    }
}

// ---------------- launcher ---------------------------------------------------
extern "C" void kernel_launch(void* const* d_in, const int* in_sizes, int n_in,
                              void* d_out, int out_size, void* d_ws, size_t ws_size,
                              hipStream_t stream)
{
    const float* nf    = (const float*)d_in[0];
    const float* frac  = (const float*)d_in[1];
    const float* lat   = (const float*)d_in[2];
    const int*   eidx  = (const int*)  d_in[3];
    const int*   n2g   = (const int*)  d_in[4];
    const float* fdiff = (const float*)d_in[5];
    const float* gamma = (const float*)d_in[6];
    const float* beta  = (const float*)d_in[7];
    const float* Wq    = (const float*)d_in[8];
    const float* bq    = (const float*)d_in[9];
    const float* Wk    = (const float*)d_in[10];
    const float* bk    = (const float*)d_in[11];
    const float* Wv    = (const float*)d_in[12];
    const float* bv    = (const float*)d_in[13];
    const float* We    = (const float*)d_in[14];
    const float* Wsk   = (const float*)d_in[15];
    const float* bsk   = (const float*)d_in[16];
    float* out = (float*)d_out;

    // workspace layout
    float* qsq       = (float*)d_ws;                               // N*880
    float* bias_all  = qsq + (size_t)N_NODES * 880;                // 1920
    float* sorted_fd = bias_all + NPAD;                            // E*3
    unsigned short* xb    = (unsigned short*)(sorted_fd + (size_t)N_EDGES * 3); // N*160
    unsigned short* wallT = xb + (size_t)N_NODES * KPAD;           // 1920*160
    unsigned short* kv    = wallT + (size_t)NPAD * KPAD;           // N*1024
    int* hist       = (int*)(kv + (size_t)N_NODES * 1024);         // N
    int* offsets    = hist + N_NODES;                              // N+1
    int* cursor     = offsets + N_NODES + 1;                       // N
    int* sorted_src = cursor + N_NODES;                            // E

    zero_hist_kernel<<<(N_NODES + 255) / 256, 256, 0, stream>>>(hist);
    hist_kernel<<<(N_EDGES + 255) / 256, 256, 0, stream>>>(eidx, hist);
    scan_kernel<<<1, 1024, 0, stream>>>(hist, offsets, cursor);
    scatter_kernel<<<(N_EDGES + 255) / 256, 256, 0, stream>>>(
        eidx, fdiff, cursor, sorted_src, sorted_fd);

    prep_kernel<<<(N_NODES + 3) / 4, 256, 0, stream>>>(
        nf, frac, lat, n2g, gamma, beta, xb);

    wall_kernel<<<(1664 * KPAD + 255) / 256, 256, 0, stream>>>(
        Wq, bq, Wk, bk, Wv, bv, Wsk, bsk, wallT, bias_all);
    wqe_kernel<<<(240 * KPAD + 255) / 256, 256, 0, stream>>>(
        Wq, bq, We, wallT, bias_all);

    dim3 ggrid(NPAD / 128, (N_NODES + 63) / 64);
    mfma_gemm_kernel<<<ggrid, 256, 0, stream>>>(xb, wallT, bias_all, qsq, kv);

    gather_kernel<<<N_NODES, 256, 0, stream>>>(
        qsq, kv, We, offsets, sorted_src, sorted_fd, nf, out);
}

// Round 4
// 188.787 us; speedup vs baseline: 4.3658x; 1.1040x over previous
//
#include <hip/hip_runtime.h>
#include <math.h>

#define N_NODES 10000
#define N_EDGES 100000
#define HIDDEN  128
#define NHEAD   4
#define CHAN    128
#define IN_DIM  137      // 128 + 6 + 3
#define KPAD    160      // padded K for MFMA
#define NCOLS   1904     // 512*3 + 128 + 240
#define NPAD    1920     // padded to 15*128
#define LATD    6
#define DISD    3

typedef __attribute__((ext_vector_type(8))) short short8v;
typedef __attribute__((ext_vector_type(4))) float float4v;

__device__ inline unsigned short f2bf(float f) {
    unsigned u = __float_as_uint(f);
    unsigned r = 0x7fffu + ((u >> 16) & 1u);
    return (unsigned short)((u + r) >> 16);
}
__device__ inline float bf2f(unsigned short u) {
    return __uint_as_float(((unsigned)u) << 16);
}

// ---------------- Kernel 0b: histogram of dst -------------------------------
__global__ __launch_bounds__(256) void hist_kernel(
    const int* __restrict__ eidx, int* __restrict__ hist)
{
    int e = blockIdx.x * 256 + threadIdx.x;
    if (e < N_EDGES) atomicAdd(&hist[eidx[N_EDGES + e]], 1);
}

// ---------------- Kernel 0c: exclusive scan (single block) ------------------
__global__ __launch_bounds__(1024) void scan_kernel(
    const int* __restrict__ hist, int* __restrict__ offsets, int* __restrict__ cursor)
{
    __shared__ int part[1024];
    const int t = threadIdx.x;
    const int base = t * 10;
    int loc[10];
    int s = 0;
    #pragma unroll
    for (int i = 0; i < 10; ++i) {
        int v = (base + i < N_NODES) ? hist[base + i] : 0;
        loc[i] = s; s += v;
    }
    part[t] = s;
    __syncthreads();
    for (int off = 1; off < 1024; off <<= 1) {
        int v = (t >= off) ? part[t - off] : 0;
        __syncthreads();
        part[t] += v;
        __syncthreads();
    }
    int pre = (t > 0) ? part[t - 1] : 0;
    #pragma unroll
    for (int i = 0; i < 10; ++i)
        if (base + i < N_NODES) {
            offsets[base + i] = pre + loc[i];
            cursor[base + i]  = pre + loc[i];
        }
    if (t == 1023) offsets[N_NODES] = part[1023];
}

// ---------------- Kernel 0d: scatter edges into dst-sorted order ------------
__global__ __launch_bounds__(256) void scatter_kernel(
    const int* __restrict__ eidx, const float* __restrict__ fdiff,
    int* __restrict__ cursor, int* __restrict__ sorted_src,
    float* __restrict__ sorted_fd)
{
    int e = blockIdx.x * 256 + threadIdx.x;
    if (e >= N_EDGES) return;
    int src = eidx[e];
    int dst = eidx[N_EDGES + e];
    int pos = atomicAdd(&cursor[dst], 1);
    sorted_src[pos] = src;
    sorted_fd[pos * 3 + 0] = fdiff[e * 3 + 0];
    sorted_fd[pos * 3 + 1] = fdiff[e * 3 + 1];
    sorted_fd[pos * 3 + 2] = fdiff[e * 3 + 2];
}

// ---------------- Kernel 1: LayerNorm + concat -> bf16 x [N][160]; zero hist -
__global__ __launch_bounds__(256) void prep_kernel(
    const float* __restrict__ nf, const float* __restrict__ frac,
    const float* __restrict__ lat, const int* __restrict__ n2g,
    const float* __restrict__ gamma, const float* __restrict__ beta,
    unsigned short* __restrict__ xb, int* __restrict__ hist)
{
    int wave = threadIdx.x >> 6;
    int lane = threadIdx.x & 63;
    int n = blockIdx.x * 4 + wave;
    if (n >= N_NODES) return;

    float v0 = nf[n * HIDDEN + lane];
    float v1 = nf[n * HIDDEN + 64 + lane];
    float s  = v0 + v1;
    float sq = v0 * v0 + v1 * v1;
    #pragma unroll
    for (int m = 1; m < 64; m <<= 1) {
        s  += __shfl_xor(s, m);
        sq += __shfl_xor(sq, m);
    }
    float mean = s * (1.0f / 128.0f);
    float var  = sq * (1.0f / 128.0f) - mean * mean;   // biased variance
    float inv  = rsqrtf(var + 1e-5f);

    xb[n * KPAD + lane]      = f2bf((v0 - mean) * inv * gamma[lane]      + beta[lane]);
    xb[n * KPAD + 64 + lane] = f2bf((v1 - mean) * inv * gamma[64 + lane] + beta[64 + lane]);
    if (lane < LATD) xb[n * KPAD + HIDDEN + lane]        = f2bf(lat[n2g[n] * LATD + lane]);
    if (lane < DISD) xb[n * KPAD + HIDDEN + LATD + lane] = f2bf(frac[n * DISD + lane]);
    if (lane >= 41)  xb[n * KPAD + 96 + lane] = 0;      // cols 137..159 zero-pad
    if (lane == 0)   hist[n] = 0;
}

// ---------------- Kernel 2: WallT bf16 (q,k,v,skip + fused Wqe) + biases -----
__global__ __launch_bounds__(256) void weights_kernel(
    const float* __restrict__ Wq, const float* __restrict__ bq,
    const float* __restrict__ Wk, const float* __restrict__ bk,
    const float* __restrict__ Wv, const float* __restrict__ bv,
    const float* __restrict__ Wsk, const float* __restrict__ bsk,
    const float* __restrict__ We,
    unsigned short* __restrict__ wallT, float* __restrict__ bias_all)
{
    int idx = blockIdx.x * 256 + threadIdx.x;   // < 1904*160
    int n = idx / KPAD, k = idx % KPAD;
    if (n < 1664) {
        float val = 0.0f;
        if (k < IN_DIM) {
            if (n < 512)        val = Wq[(size_t)k * 512 + n];
            else if (n < 1024)  val = Wk[(size_t)k * 512 + (n - 512)];
            else if (n < 1536)  val = Wv[(size_t)k * 512 + (n - 1024)];
            else                val = Wsk[(size_t)k * 128 + (n - 1536)];
        }
        wallT[idx] = f2bf(val);
        if (k == 0) {
            float b;
            if (n < 512)        b = bq[n];
            else if (n < 1024)  b = bk[n - 512];
            else if (n < 1536)  b = bv[n - 1024];
            else                b = bsk[n - 1536];
            bias_all[n] = b;
        }
    } else {
        int hj = n - 1664;                      // 0..239
        int h = hj / 60, j = hj % 60;
        float s = 0.0f;
        if (k < IN_DIM) {
            #pragma unroll 4
            for (int c = 0; c < 128; ++c)
                s += Wq[(size_t)k * 512 + h * 128 + c] * We[(size_t)j * 512 + h * 128 + c];
        }
        wallT[idx] = f2bf(s);
        if (k == KPAD - 1) {
            float b = 0.0f;
            #pragma unroll 4
            for (int c = 0; c < 128; ++c)
                b += bq[h * 128 + c] * We[(size_t)j * 512 + h * 128 + c];
            bias_all[n] = b;
        }
    }
}

// ---------------- Kernel 3: MFMA GEMM xb[N,160] @ WallT^T -> qsq f32, kv bf16
__global__ __launch_bounds__(256) void mfma_gemm_kernel(
    const unsigned short* __restrict__ xb, const unsigned short* __restrict__ wallT,
    const float* __restrict__ bias_all,
    float* __restrict__ qsq, unsigned short* __restrict__ kv)
{
    __shared__ __align__(16) unsigned short Alds[64 * 168];
    __shared__ __align__(16) unsigned short Blds[128 * 168];
    const int row0 = blockIdx.y * 64;
    const int col0 = blockIdx.x * 128;
    const int tid  = threadIdx.x;

    for (int i = tid; i < 64 * 20; i += 256) {       // A: 64 rows x 160 bf16
        int r = i / 20, c8 = (i % 20) * 8;
        uint4 v = make_uint4(0u, 0u, 0u, 0u);
        if (row0 + r < N_NODES)
            v = *reinterpret_cast<const uint4*>(&xb[(size_t)(row0 + r) * KPAD + c8]);
        *reinterpret_cast<uint4*>(&Alds[r * 168 + c8]) = v;
    }
    for (int i = tid; i < 128 * 20; i += 256) {      // B: 128 cols x 160 bf16
        int n = i / 20, c8 = (i % 20) * 8;
        uint4 v = *reinterpret_cast<const uint4*>(&wallT[(size_t)(col0 + n) * KPAD + c8]);
        *reinterpret_cast<uint4*>(&Blds[n * 168 + c8]) = v;
    }
    __syncthreads();

    const int l   = tid & 63;
    const int wid = tid >> 6;
    const int wr  = (wid >> 1) * 32;
    const int wc  = (wid & 1) * 64;
    const int lr  = l & 15;
    const int lk  = (l >> 4) * 8;

    float4v acc[2][4];
    #pragma unroll
    for (int tr = 0; tr < 2; ++tr)
        #pragma unroll
        for (int tc = 0; tc < 4; ++tc)
            acc[tr][tc] = (float4v){0.0f, 0.0f, 0.0f, 0.0f};

    #pragma unroll
    for (int ks = 0; ks < 5; ++ks) {
        short8v a[2], b[4];
        #pragma unroll
        for (int t = 0; t < 2; ++t)
            a[t] = *reinterpret_cast<const short8v*>(&Alds[(wr + t * 16 + lr) * 168 + ks * 32 + lk]);
        #pragma unroll
        for (int t = 0; t < 4; ++t)
            b[t] = *reinterpret_cast<const short8v*>(&Blds[(wc + t * 16 + lr) * 168 + ks * 32 + lk]);
        #pragma unroll
        for (int tr = 0; tr < 2; ++tr)
            #pragma unroll
            for (int tc = 0; tc < 4; ++tc)
                acc[tr][tc] = __builtin_amdgcn_mfma_f32_16x16x32_bf16(a[tr], b[tc], acc[tr][tc], 0, 0, 0);
    }

    #pragma unroll
    for (int tr = 0; tr < 2; ++tr) {
        #pragma unroll
        for (int tc = 0; tc < 4; ++tc) {
            const int col  = col0 + wc + tc * 16 + lr;
            const float bias = bias_all[col];
            #pragma unroll
            for (int j = 0; j < 4; ++j) {
                const int row = row0 + wr + tr * 16 + (l >> 4) * 4 + j;
                if (row < N_NODES) {
                    float val = acc[tr][tc][j] + bias;
                    if (col < 512)
                        qsq[(size_t)row * 880 + col] = val;
                    else if (col < 1536)
                        kv[(size_t)row * 1024 + (col - 512)] = f2bf(val);
                    else if (col < NCOLS)
                        qsq[(size_t)row * 880 + (col - 1024)] = val;
                }
            }
        }
    }
}

// ---------------- Kernel 4: per-node gather, half-wave per edge, unroll 2 ----
// Block = 1 node, wave = head. Half-wave (32 lanes, 4 ch/lane) owns one edge;
// unroll 2 => 4 edges & 8 gathers in flight per wave per iteration.
__global__ __launch_bounds__(256) void gather_kernel(
    const float* __restrict__ qsq, const unsigned short* __restrict__ kv,
    const float* __restrict__ We,
    const int* __restrict__ offsets, const int* __restrict__ sorted_src,
    const float* __restrict__ sorted_fd, const float* __restrict__ nf,
    float* __restrict__ out)
{
    __shared__ float headout[NHEAD][CHAN];
    const int n    = blockIdx.x;
    const int h    = threadIdx.x >> 6;
    const int l    = threadIdx.x & 63;
    const int hl   = l & 31;
    const int half = l >> 5;
    const float TWO_PI = 6.283185307179586f;
    const float scale  = 0.08838834764831845f;   // 1/sqrt(128)

    const size_t nrow = (size_t)n * 880;
    const float4 q4  = *reinterpret_cast<const float4*>(&qsq[nrow + h * 128 + 4 * hl]);
    const float qe_a = qsq[nrow + 640 + h * 60 + hl];          // j1 = hl (<60 always)
    const bool  v2ok = (hl < 28);                              // j2 = hl+32 < 60
    const float qe_b = v2ok ? qsq[nrow + 640 + h * 60 + hl + 32] : 0.0f;

    // emb slot 1: j1 = hl; slot 2: j2 = hl+32 (always cos)
    const int   jj1  = (hl < 30) ? hl : hl - 30;
    const int   sd1  = jj1 / 10;
    const float fc1  = TWO_PI * (float)(jj1 % 10);
    const bool  sin1 = (hl < 30);
    const int   jj2  = hl + 2;
    const int   sd2  = v2ok ? (jj2 / 10) : 0;
    const float fc2  = v2ok ? TWO_PI * (float)(jj2 % 10) : 0.0f;

    float ax = 0.f, ay = 0.f, az = 0.f, aw = 0.f;
    float agg1 = 0.f, agg2 = 0.f, sumw = 0.f;
    const int e0 = offsets[n], e1 = offsets[n + 1];

    for (int base = e0; base < e1; base += 4) {
        const int eA = base + half;
        const int eB = base + half + 2;
        const bool okA = (eA < e1), okB = (eB < e1);
        const int iA = okA ? eA : e0;
        const int iB = okB ? eB : e0;
        const int srcA = sorted_src[iA];
        const int srcB = sorted_src[iB];
        const float fdA1 = sorted_fd[iA * 3 + sd1];
        const float fdA2 = sorted_fd[iA * 3 + sd2];
        const float fdB1 = sorted_fd[iB * 3 + sd1];
        const float fdB2 = sorted_fd[iB * 3 + sd2];
        const unsigned short* pA = &kv[(size_t)srcA * 1024 + h * 128 + 4 * hl];
        const unsigned short* pB = &kv[(size_t)srcB * 1024 + h * 128 + 4 * hl];
        const ushort4 kA = *reinterpret_cast<const ushort4*>(pA);
        const ushort4 vA = *reinterpret_cast<const ushort4*>(pA + 512);
        const ushort4 kB = *reinterpret_cast<const ushort4*>(pB);
        const ushort4 vB = *reinterpret_cast<const ushort4*>(pB + 512);

        const float eA1 = sin1 ? __sinf(fdA1 * fc1) : __cosf(fdA1 * fc1);
        const float eA2 = __cosf(fdA2 * fc2);
        const float eB1 = sin1 ? __sinf(fdB1 * fc1) : __cosf(fdB1 * fc1);
        const float eB2 = __cosf(fdB2 * fc2);

        float pAs = q4.x * bf2f(kA.x) + q4.y * bf2f(kA.y)
                  + q4.z * bf2f(kA.z) + q4.w * bf2f(kA.w)
                  + eA1 * qe_a + eA2 * qe_b;
        float pBs = q4.x * bf2f(kB.x) + q4.y * bf2f(kB.y)
                  + q4.z * bf2f(kB.z) + q4.w * bf2f(kB.w)
                  + eB1 * qe_a + eB2 * qe_b;
        #pragma unroll
        for (int m = 1; m <= 16; m <<= 1) {
            pAs += __shfl_xor(pAs, m);
            pBs += __shfl_xor(pBs, m);
        }
        const float wA = okA ? __expf(pAs * scale) : 0.0f;
        const float wB = okB ? __expf(pBs * scale) : 0.0f;
        sumw += wA + wB;
        ax += wA * bf2f(vA.x) + wB * bf2f(vB.x);
        ay += wA * bf2f(vA.y) + wB * bf2f(vB.y);
        az += wA * bf2f(vA.z) + wB * bf2f(vB.z);
        aw += wA * bf2f(vA.w) + wB * bf2f(vB.w);
        agg1 += wA * eA1 + wB * eB1;
        if (v2ok) agg2 += wA * eA2 + wB * eB2;
    }

    // combine the two halves
    sumw += __shfl_xor(sumw, 32);
    ax += __shfl_xor(ax, 32);  ay += __shfl_xor(ay, 32);
    az += __shfl_xor(az, 32);  aw += __shfl_xor(aw, 32);
    agg1 += __shfl_xor(agg1, 32);
    agg2 += __shfl_xor(agg2, 32);

    // e-contribution: (sum_e w*emb) @ We_head
    #pragma unroll 4
    for (int j = 0; j < 60; ++j) {
        const float a = (j < 32) ? __shfl(agg1, j) : __shfl(agg2, j - 32);
        const float4 w4 = *reinterpret_cast<const float4*>(&We[j * 512 + h * 128 + 4 * hl]);
        ax += a * w4.x;  ay += a * w4.y;  az += a * w4.z;  aw += a * w4.w;
    }

    if (half == 0) {
        const float inv = 1.0f / (sumw + 1e-16f);
        float4 r;
        r.x = ax * inv; r.y = ay * inv; r.z = az * inv; r.w = aw * inv;
        *reinterpret_cast<float4*>(&headout[h][4 * hl]) = r;
    }
    __syncthreads();

    if (threadIdx.x < CHAN) {
        const int c = threadIdx.x;
        float z = 0.25f * (headout[0][c] + headout[1][c] + headout[2][c] + headout[3][c])
                + qsq[nrow + 512 + c];                       // skip
        float si = z / (1.0f + __expf(-z));
        out[n * CHAN + c] = nf[n * CHAN + c] + si;
    }
}

// ---------------- launcher ---------------------------------------------------
extern "C" void kernel_launch(void* const* d_in, const int* in_sizes, int n_in,
                              void* d_out, int out_size, void* d_ws, size_t ws_size,
                              hipStream_t stream)
{
    const float* nf    = (const float*)d_in[0];
    const float* frac  = (const float*)d_in[1];
    const float* lat   = (const float*)d_in[2];
    const int*   eidx  = (const int*)  d_in[3];
    const int*   n2g   = (const int*)  d_in[4];
    const float* fdiff = (const float*)d_in[5];
    const float* gamma = (const float*)d_in[6];
    const float* beta  = (const float*)d_in[7];
    const float* Wq    = (const float*)d_in[8];
    const float* bq    = (const float*)d_in[9];
    const float* Wk    = (const float*)d_in[10];
    const float* bk    = (const float*)d_in[11];
    const float* Wv    = (const float*)d_in[12];
    const float* bv    = (const float*)d_in[13];
    const float* We    = (const float*)d_in[14];
    const float* Wsk   = (const float*)d_in[15];
    const float* bsk   = (const float*)d_in[16];
    float* out = (float*)d_out;

    // workspace layout
    float* qsq       = (float*)d_ws;                               // N*880
    float* bias_all  = qsq + (size_t)N_NODES * 880;                // 1920
    float* sorted_fd = bias_all + NPAD;                            // E*3
    unsigned short* xb    = (unsigned short*)(sorted_fd + (size_t)N_EDGES * 3); // N*160
    unsigned short* wallT = xb + (size_t)N_NODES * KPAD;           // 1920*160
    unsigned short* kv    = wallT + (size_t)NPAD * KPAD;           // N*1024
    int* hist       = (int*)(kv + (size_t)N_NODES * 1024);         // N
    int* offsets    = hist + N_NODES;                              // N+1
    int* cursor     = offsets + N_NODES + 1;                       // N
    int* sorted_src = cursor + N_NODES;                            // E

    prep_kernel<<<(N_NODES + 3) / 4, 256, 0, stream>>>(
        nf, frac, lat, n2g, gamma, beta, xb, hist);
    hist_kernel<<<(N_EDGES + 255) / 256, 256, 0, stream>>>(eidx, hist);
    scan_kernel<<<1, 1024, 0, stream>>>(hist, offsets, cursor);
    scatter_kernel<<<(N_EDGES + 255) / 256, 256, 0, stream>>>(
        eidx, fdiff, cursor, sorted_src, sorted_fd);

    weights_kernel<<<(NCOLS * KPAD) / 256, 256, 0, stream>>>(
        Wq, bq, Wk, bk, Wv, bv, Wsk, bsk, We, wallT, bias_all);

    dim3 ggrid(NPAD / 128, (N_NODES + 63) / 64);
    mfma_gemm_kernel<<<ggrid, 256, 0, stream>>>(xb, wallT, bias_all, qsq, kv);

    gather_kernel<<<N_NODES, 256, 0, stream>>>(
        qsq, kv, We, offsets, sorted_src, sorted_fd, nf, out);
}

// Round 5
// 180.501 us; speedup vs baseline: 4.5662x; 1.0459x over previous
//
#include <hip/hip_runtime.h>
#include <math.h>

#define N_NODES 10000
#define N_EDGES 100000
#define HIDDEN  128
#define NHEAD   4
#define CHAN    128
#define IN_DIM  137      // 128 + 6 + 3
#define KPAD    160      // padded K for MFMA
#define NCOLS   1904     // 512*3 + 128 + 240
#define NPAD    1920     // padded to 15*128
#define LATD    6
#define DISD    3

typedef __attribute__((ext_vector_type(8))) short short8v;
typedef __attribute__((ext_vector_type(4))) float float4v;

__device__ inline unsigned short f2bf(float f) {
    unsigned u = __float_as_uint(f);
    unsigned r = 0x7fffu + ((u >> 16) & 1u);
    return (unsigned short)((u + r) >> 16);
}
__device__ inline float bf2f(unsigned short u) {
    return __uint_as_float(((unsigned)u) << 16);
}

// ---------------- Kernel 0b: histogram of dst -------------------------------
__global__ __launch_bounds__(256) void hist_kernel(
    const int* __restrict__ eidx, int* __restrict__ hist)
{
    int e = blockIdx.x * 256 + threadIdx.x;
    if (e < N_EDGES) atomicAdd(&hist[eidx[N_EDGES + e]], 1);
}

// ---------------- Kernel 0c: exclusive scan (single block) ------------------
__global__ __launch_bounds__(1024) void scan_kernel(
    const int* __restrict__ hist, int* __restrict__ offsets, int* __restrict__ cursor)
{
    __shared__ int part[1024];
    const int t = threadIdx.x;
    const int base = t * 10;
    int loc[10];
    int s = 0;
    #pragma unroll
    for (int i = 0; i < 10; ++i) {
        int v = (base + i < N_NODES) ? hist[base + i] : 0;
        loc[i] = s; s += v;
    }
    part[t] = s;
    __syncthreads();
    for (int off = 1; off < 1024; off <<= 1) {
        int v = (t >= off) ? part[t - off] : 0;
        __syncthreads();
        part[t] += v;
        __syncthreads();
    }
    int pre = (t > 0) ? part[t - 1] : 0;
    #pragma unroll
    for (int i = 0; i < 10; ++i)
        if (base + i < N_NODES) {
            offsets[base + i] = pre + loc[i];
            cursor[base + i]  = pre + loc[i];
        }
    if (t == 1023) offsets[N_NODES] = part[1023];
}

// ---------------- Kernel 0d: scatter edges into dst-sorted order ------------
__global__ __launch_bounds__(256) void scatter_kernel(
    const int* __restrict__ eidx, const float* __restrict__ fdiff,
    int* __restrict__ cursor, int* __restrict__ sorted_src,
    float* __restrict__ sorted_fd)
{
    int e = blockIdx.x * 256 + threadIdx.x;
    if (e >= N_EDGES) return;
    int src = eidx[e];
    int dst = eidx[N_EDGES + e];
    int pos = atomicAdd(&cursor[dst], 1);
    sorted_src[pos] = src;
    sorted_fd[pos * 3 + 0] = fdiff[e * 3 + 0];
    sorted_fd[pos * 3 + 1] = fdiff[e * 3 + 1];
    sorted_fd[pos * 3 + 2] = fdiff[e * 3 + 2];
}

// ---------------- Kernel 1: LayerNorm + concat -> bf16 x [N][160]; zero hist -
__global__ __launch_bounds__(256) void prep_kernel(
    const float* __restrict__ nf, const float* __restrict__ frac,
    const float* __restrict__ lat, const int* __restrict__ n2g,
    const float* __restrict__ gamma, const float* __restrict__ beta,
    unsigned short* __restrict__ xb, int* __restrict__ hist)
{
    int wave = threadIdx.x >> 6;
    int lane = threadIdx.x & 63;
    int n = blockIdx.x * 4 + wave;
    if (n >= N_NODES) return;

    float v0 = nf[n * HIDDEN + lane];
    float v1 = nf[n * HIDDEN + 64 + lane];
    float s  = v0 + v1;
    float sq = v0 * v0 + v1 * v1;
    #pragma unroll
    for (int m = 1; m < 64; m <<= 1) {
        s  += __shfl_xor(s, m);
        sq += __shfl_xor(sq, m);
    }
    float mean = s * (1.0f / 128.0f);
    float var  = sq * (1.0f / 128.0f) - mean * mean;   // biased variance
    float inv  = rsqrtf(var + 1e-5f);

    xb[n * KPAD + lane]      = f2bf((v0 - mean) * inv * gamma[lane]      + beta[lane]);
    xb[n * KPAD + 64 + lane] = f2bf((v1 - mean) * inv * gamma[64 + lane] + beta[64 + lane]);
    if (lane < LATD) xb[n * KPAD + HIDDEN + lane]        = f2bf(lat[n2g[n] * LATD + lane]);
    if (lane < DISD) xb[n * KPAD + HIDDEN + LATD + lane] = f2bf(frac[n * DISD + lane]);
    if (lane >= 41)  xb[n * KPAD + 96 + lane] = 0;      // cols 137..159 zero-pad
    if (lane == 0)   hist[n] = 0;
}

// ---------------- Kernel 2: WallT bf16 (q,k,v,skip + fused Wqe) + Webt -------
__global__ __launch_bounds__(256) void weights_kernel(
    const float* __restrict__ Wq, const float* __restrict__ bq,
    const float* __restrict__ Wk, const float* __restrict__ bk,
    const float* __restrict__ Wv, const float* __restrict__ bv,
    const float* __restrict__ Wsk, const float* __restrict__ bsk,
    const float* __restrict__ We,
    unsigned short* __restrict__ wallT, float* __restrict__ bias_all,
    unsigned short* __restrict__ webt)
{
    int idx = blockIdx.x * 256 + threadIdx.x;   // < 1904*160 + 4*128*64
    if (idx < NCOLS * KPAD) {
        int n = idx / KPAD, k = idx % KPAD;
        if (n < 1664) {
            float val = 0.0f;
            if (k < IN_DIM) {
                if (n < 512)        val = Wq[(size_t)k * 512 + n];
                else if (n < 1024)  val = Wk[(size_t)k * 512 + (n - 512)];
                else if (n < 1536)  val = Wv[(size_t)k * 512 + (n - 1024)];
                else                val = Wsk[(size_t)k * 128 + (n - 1536)];
            }
            wallT[idx] = f2bf(val);
            if (k == 0) {
                float b;
                if (n < 512)        b = bq[n];
                else if (n < 1024)  b = bk[n - 512];
                else if (n < 1536)  b = bv[n - 1024];
                else                b = bsk[n - 1536];
                bias_all[n] = b;
            }
        } else {
            int hj = n - 1664;                      // 0..239
            int h = hj / 60, j = hj % 60;
            float s = 0.0f;
            if (k < IN_DIM) {
                #pragma unroll 4
                for (int c = 0; c < 128; ++c)
                    s += Wq[(size_t)k * 512 + h * 128 + c] * We[(size_t)j * 512 + h * 128 + c];
            }
            wallT[idx] = f2bf(s);
            if (k == KPAD - 1) {
                float b = 0.0f;
                #pragma unroll 4
                for (int c = 0; c < 128; ++c)
                    b += bq[h * 128 + c] * We[(size_t)j * 512 + h * 128 + c];
                bias_all[n] = b;
            }
        }
    } else {
        int g = idx - NCOLS * KPAD;                 // webt[h][c][j], 4*128*64
        int h = g >> 13, c = (g >> 6) & 127, j = g & 63;
        float v = (j < 60) ? We[(size_t)j * 512 + h * 128 + c] : 0.0f;
        webt[g] = f2bf(v);
    }
}

// ---------------- Kernel 3: MFMA GEMM xb[N,160] @ WallT^T -> qsq f32, kv bf16
__global__ __launch_bounds__(256) void mfma_gemm_kernel(
    const unsigned short* __restrict__ xb, const unsigned short* __restrict__ wallT,
    const float* __restrict__ bias_all,
    float* __restrict__ qsq, unsigned short* __restrict__ kv)
{
    __shared__ __align__(16) unsigned short Alds[64 * 168];
    __shared__ __align__(16) unsigned short Blds[128 * 168];
    const int row0 = blockIdx.y * 64;
    const int col0 = blockIdx.x * 128;
    const int tid  = threadIdx.x;

    for (int i = tid; i < 64 * 20; i += 256) {       // A: 64 rows x 160 bf16
        int r = i / 20, c8 = (i % 20) * 8;
        uint4 v = make_uint4(0u, 0u, 0u, 0u);
        if (row0 + r < N_NODES)
            v = *reinterpret_cast<const uint4*>(&xb[(size_t)(row0 + r) * KPAD + c8]);
        *reinterpret_cast<uint4*>(&Alds[r * 168 + c8]) = v;
    }
    for (int i = tid; i < 128 * 20; i += 256) {      // B: 128 cols x 160 bf16
        int n = i / 20, c8 = (i % 20) * 8;
        uint4 v = *reinterpret_cast<const uint4*>(&wallT[(size_t)(col0 + n) * KPAD + c8]);
        *reinterpret_cast<uint4*>(&Blds[n * 168 + c8]) = v;
    }
    __syncthreads();

    const int l   = tid & 63;
    const int wid = tid >> 6;
    const int wr  = (wid >> 1) * 32;
    const int wc  = (wid & 1) * 64;
    const int lr  = l & 15;
    const int lk  = (l >> 4) * 8;

    float4v acc[2][4];
    #pragma unroll
    for (int tr = 0; tr < 2; ++tr)
        #pragma unroll
        for (int tc = 0; tc < 4; ++tc)
            acc[tr][tc] = (float4v){0.0f, 0.0f, 0.0f, 0.0f};

    #pragma unroll
    for (int ks = 0; ks < 5; ++ks) {
        short8v a[2], b[4];
        #pragma unroll
        for (int t = 0; t < 2; ++t)
            a[t] = *reinterpret_cast<const short8v*>(&Alds[(wr + t * 16 + lr) * 168 + ks * 32 + lk]);
        #pragma unroll
        for (int t = 0; t < 4; ++t)
            b[t] = *reinterpret_cast<const short8v*>(&Blds[(wc + t * 16 + lr) * 168 + ks * 32 + lk]);
        #pragma unroll
        for (int tr = 0; tr < 2; ++tr)
            #pragma unroll
            for (int tc = 0; tc < 4; ++tc)
                acc[tr][tc] = __builtin_amdgcn_mfma_f32_16x16x32_bf16(a[tr], b[tc], acc[tr][tc], 0, 0, 0);
    }

    #pragma unroll
    for (int tr = 0; tr < 2; ++tr) {
        #pragma unroll
        for (int tc = 0; tc < 4; ++tc) {
            const int col  = col0 + wc + tc * 16 + lr;
            const float bias = bias_all[col];
            #pragma unroll
            for (int j = 0; j < 4; ++j) {
                const int row = row0 + wr + tr * 16 + (l >> 4) * 4 + j;
                if (row < N_NODES) {
                    float val = acc[tr][tc][j] + bias;
                    if (col < 512)
                        qsq[(size_t)row * 880 + col] = val;
                    else if (col < 1536)
                        kv[(size_t)row * 1024 + (col - 512)] = f2bf(val);
                    else if (col < NCOLS)
                        qsq[(size_t)row * 880 + (col - 1024)] = val;
                }
            }
        }
    }
}

// ---------------- Kernel 4: per-node gather; raw sums written back into qsq --
// Block = 1 node, wave = head, half-wave per edge, unroll 2.
// After main loop + block barrier: av (raw Σw*v) -> qsq cols [h*128,h*128+128)
// aggemb bf16 -> qsq cols 640..767 (as 256 ushorts), sumw -> col 768+h.
__global__ __launch_bounds__(256) void gather_kernel(
    float* __restrict__ qsq, const unsigned short* __restrict__ kv,
    const int* __restrict__ offsets, const int* __restrict__ sorted_src,
    const float* __restrict__ sorted_fd)
{
    const int n    = blockIdx.x;
    const int h    = threadIdx.x >> 6;
    const int l    = threadIdx.x & 63;
    const int hl   = l & 31;
    const int half = l >> 5;
    const float TWO_PI = 6.283185307179586f;
    const float scale  = 0.08838834764831845f;   // 1/sqrt(128)

    float* row = qsq + (size_t)n * 880;
    const float4 q4  = *reinterpret_cast<const float4*>(&row[h * 128 + 4 * hl]);
    const float qe_a = row[640 + h * 60 + hl];                 // j1 = hl (<60 always)
    const bool  v2ok = (hl < 28);                              // j2 = hl+32 < 60
    const float qe_b = v2ok ? row[640 + h * 60 + hl + 32] : 0.0f;

    // emb slot 1: j1 = hl; slot 2: j2 = hl+32 (always cos)
    const int   jj1  = (hl < 30) ? hl : hl - 30;
    const int   sd1  = jj1 / 10;
    const float fc1  = TWO_PI * (float)(jj1 % 10);
    const bool  sin1 = (hl < 30);
    const int   jj2  = hl + 2;
    const int   sd2  = v2ok ? (jj2 / 10) : 0;
    const float fc2  = v2ok ? TWO_PI * (float)(jj2 % 10) : 0.0f;

    float ax = 0.f, ay = 0.f, az = 0.f, aw = 0.f;
    float agg1 = 0.f, agg2 = 0.f, sumw = 0.f;
    const int e0 = offsets[n], e1 = offsets[n + 1];

    for (int base = e0; base < e1; base += 4) {
        const int eA = base + half;
        const int eB = base + half + 2;
        const bool okA = (eA < e1), okB = (eB < e1);
        const int iA = okA ? eA : e0;
        const int iB = okB ? eB : e0;
        const int srcA = sorted_src[iA];
        const int srcB = sorted_src[iB];
        const float fdA1 = sorted_fd[iA * 3 + sd1];
        const float fdA2 = sorted_fd[iA * 3 + sd2];
        const float fdB1 = sorted_fd[iB * 3 + sd1];
        const float fdB2 = sorted_fd[iB * 3 + sd2];
        const unsigned short* pA = &kv[(size_t)srcA * 1024 + h * 128 + 4 * hl];
        const unsigned short* pB = &kv[(size_t)srcB * 1024 + h * 128 + 4 * hl];
        const ushort4 kA = *reinterpret_cast<const ushort4*>(pA);
        const ushort4 vA = *reinterpret_cast<const ushort4*>(pA + 512);
        const ushort4 kB = *reinterpret_cast<const ushort4*>(pB);
        const ushort4 vB = *reinterpret_cast<const ushort4*>(pB + 512);

        const float eA1 = sin1 ? __sinf(fdA1 * fc1) : __cosf(fdA1 * fc1);
        const float eA2 = __cosf(fdA2 * fc2);
        const float eB1 = sin1 ? __sinf(fdB1 * fc1) : __cosf(fdB1 * fc1);
        const float eB2 = __cosf(fdB2 * fc2);

        float pAs = q4.x * bf2f(kA.x) + q4.y * bf2f(kA.y)
                  + q4.z * bf2f(kA.z) + q4.w * bf2f(kA.w)
                  + eA1 * qe_a + eA2 * qe_b;
        float pBs = q4.x * bf2f(kB.x) + q4.y * bf2f(kB.y)
                  + q4.z * bf2f(kB.z) + q4.w * bf2f(kB.w)
                  + eB1 * qe_a + eB2 * qe_b;
        #pragma unroll
        for (int m = 1; m <= 16; m <<= 1) {
            pAs += __shfl_xor(pAs, m);
            pBs += __shfl_xor(pBs, m);
        }
        const float wA = okA ? __expf(pAs * scale) : 0.0f;
        const float wB = okB ? __expf(pBs * scale) : 0.0f;
        sumw += wA + wB;
        ax += wA * bf2f(vA.x) + wB * bf2f(vB.x);
        ay += wA * bf2f(vA.y) + wB * bf2f(vB.y);
        az += wA * bf2f(vA.z) + wB * bf2f(vB.z);
        aw += wA * bf2f(vA.w) + wB * bf2f(vB.w);
        agg1 += wA * eA1 + wB * eB1;
        if (v2ok) agg2 += wA * eA2 + wB * eB2;
    }

    // combine the two halves
    sumw += __shfl_xor(sumw, 32);
    ax += __shfl_xor(ax, 32);  ay += __shfl_xor(ay, 32);
    az += __shfl_xor(az, 32);  aw += __shfl_xor(aw, 32);
    agg1 += __shfl_xor(agg1, 32);
    agg2 += __shfl_xor(agg2, 32);

    // barrier: all waves' q/qe reads must complete before aliased writes
    __syncthreads();

    if (half == 0) {
        float4 r;
        r.x = ax; r.y = ay; r.z = az; r.w = aw;
        *reinterpret_cast<float4*>(&row[h * 128 + 4 * hl]) = r;   // raw Σw*v
        unsigned short* us = (unsigned short*)(row + 640);        // aggemb bf16
        us[h * 64 + hl]      = f2bf(agg1);                        // j = hl
        us[h * 64 + 32 + hl] = f2bf(agg2);                        // j = hl+32 (0 pad j>=60)
        if (hl == 0) row[768 + h] = sumw;
    }
}

// ---------------- Kernel 5: corr MFMA — av += aggemb @ Webt ------------------
// Block = 64 nodes, 4 waves (wave h = head h). A: aggemb [64][256] bf16 from
// qsq cols 640.., B: webt[h][128][64]. 64 MFMAs/wave. RMW av in qsq.
__global__ __launch_bounds__(256, 1) void corr_kernel(
    const unsigned short* __restrict__ webt, float* __restrict__ qsq)
{
    __shared__ __align__(16) unsigned short Alds[64 * 264];
    __shared__ __align__(16) unsigned short Blds[512 * 72];
    const int node0 = blockIdx.x * 64;
    const int tid = threadIdx.x;

    for (int i = tid; i < 64 * 32; i += 256) {       // A: 2048 uint4
        int r = i >> 5, c8 = (i & 31) * 8;
        uint4 v = make_uint4(0u, 0u, 0u, 0u);
        if (node0 + r < N_NODES)
            v = *reinterpret_cast<const uint4*>(
                (const unsigned short*)(qsq + (size_t)(node0 + r) * 880 + 640) + c8);
        *reinterpret_cast<uint4*>(&Alds[r * 264 + c8]) = v;
    }
    for (int i = tid; i < 512 * 8; i += 256) {       // B: 4096 uint4
        int r = i >> 3, c8 = (i & 7) * 8;
        uint4 v = *reinterpret_cast<const uint4*>(&webt[r * 64 + c8]);
        *reinterpret_cast<uint4*>(&Blds[r * 72 + c8]) = v;
    }
    __syncthreads();

    const int l  = tid & 63;
    const int h  = tid >> 6;
    const int lr = l & 15;
    const int lk = (l >> 4) * 8;

    float4v acc[4][8];
    #pragma unroll
    for (int m = 0; m < 4; ++m)
        #pragma unroll
        for (int nn = 0; nn < 8; ++nn)
            acc[m][nn] = (float4v){0.0f, 0.0f, 0.0f, 0.0f};

    #pragma unroll
    for (int ks = 0; ks < 2; ++ks) {
        short8v a[4], b[8];
        #pragma unroll
        for (int m = 0; m < 4; ++m)
            a[m] = *reinterpret_cast<const short8v*>(
                &Alds[(m * 16 + lr) * 264 + h * 64 + ks * 32 + lk]);
        #pragma unroll
        for (int nn = 0; nn < 8; ++nn)
            b[nn] = *reinterpret_cast<const short8v*>(
                &Blds[(h * 128 + nn * 16 + lr) * 72 + ks * 32 + lk]);
        #pragma unroll
        for (int m = 0; m < 4; ++m)
            #pragma unroll
            for (int nn = 0; nn < 8; ++nn)
                acc[m][nn] = __builtin_amdgcn_mfma_f32_16x16x32_bf16(a[m], b[nn], acc[m][nn], 0, 0, 0);
    }

    #pragma unroll
    for (int m = 0; m < 4; ++m) {
        #pragma unroll
        for (int nn = 0; nn < 8; ++nn) {
            const int col = h * 128 + nn * 16 + lr;
            #pragma unroll
            for (int j = 0; j < 4; ++j) {
                const int rowi = node0 + m * 16 + (l >> 4) * 4 + j;
                if (rowi < N_NODES) {
                    float* p = &qsq[(size_t)rowi * 880 + col];
                    *p += acc[m][nn][j];
                }
            }
        }
    }
}

// ---------------- Kernel 6: finalize ----------------------------------------
__global__ __launch_bounds__(256) void finalize_kernel(
    const float* __restrict__ qsq, const float* __restrict__ nf,
    float* __restrict__ out)
{
    int idx = blockIdx.x * 256 + threadIdx.x;
    if (idx >= N_NODES * CHAN) return;
    int n = idx >> 7, c = idx & 127;
    const float* row = qsq + (size_t)n * 880;
    float z = 0.0f;
    #pragma unroll
    for (int h = 0; h < NHEAD; ++h)
        z += row[h * 128 + c] / (row[768 + h] + 1e-16f);
    z = 0.25f * z + row[512 + c];                   // head mean + skip
    float si = z / (1.0f + __expf(-z));             // silu
    out[idx] = nf[idx] + si;
}

// ---------------- launcher ---------------------------------------------------
extern "C" void kernel_launch(void* const* d_in, const int* in_sizes, int n_in,
                              void* d_out, int out_size, void* d_ws, size_t ws_size,
                              hipStream_t stream)
{
    const float* nf    = (const float*)d_in[0];
    const float* frac  = (const float*)d_in[1];
    const float* lat   = (const float*)d_in[2];
    const int*   eidx  = (const int*)  d_in[3];
    const int*   n2g   = (const int*)  d_in[4];
    const float* fdiff = (const float*)d_in[5];
    const float* gamma = (const float*)d_in[6];
    const float* beta  = (const float*)d_in[7];
    const float* Wq    = (const float*)d_in[8];
    const float* bq    = (const float*)d_in[9];
    const float* Wk    = (const float*)d_in[10];
    const float* bk    = (const float*)d_in[11];
    const float* Wv    = (const float*)d_in[12];
    const float* bv    = (const float*)d_in[13];
    const float* We    = (const float*)d_in[14];
    const float* Wsk   = (const float*)d_in[15];
    const float* bsk   = (const float*)d_in[16];
    float* out = (float*)d_out;

    // workspace layout
    float* qsq       = (float*)d_ws;                               // N*880
    float* bias_all  = qsq + (size_t)N_NODES * 880;                // 1920
    float* sorted_fd = bias_all + NPAD;                            // E*3
    unsigned short* xb    = (unsigned short*)(sorted_fd + (size_t)N_EDGES * 3); // N*160
    unsigned short* wallT = xb + (size_t)N_NODES * KPAD;           // 1920*160
    unsigned short* webt  = wallT + (size_t)NPAD * KPAD;           // 4*128*64
    unsigned short* kv    = webt + 4 * 128 * 64;                   // N*1024
    int* hist       = (int*)(kv + (size_t)N_NODES * 1024);         // N
    int* offsets    = hist + N_NODES;                              // N+1
    int* cursor     = offsets + N_NODES + 1;                       // N
    int* sorted_src = cursor + N_NODES;                            // E

    prep_kernel<<<(N_NODES + 3) / 4, 256, 0, stream>>>(
        nf, frac, lat, n2g, gamma, beta, xb, hist);
    hist_kernel<<<(N_EDGES + 255) / 256, 256, 0, stream>>>(eidx, hist);
    scan_kernel<<<1, 1024, 0, stream>>>(hist, offsets, cursor);
    scatter_kernel<<<(N_EDGES + 255) / 256, 256, 0, stream>>>(
        eidx, fdiff, cursor, sorted_src, sorted_fd);

    weights_kernel<<<(NCOLS * KPAD + 4 * 128 * 64) / 256, 256, 0, stream>>>(
        Wq, bq, Wk, bk, Wv, bv, Wsk, bsk, We, wallT, bias_all, webt);

    dim3 ggrid(NPAD / 128, (N_NODES + 63) / 64);
    mfma_gemm_kernel<<<ggrid, 256, 0, stream>>>(xb, wallT, bias_all, qsq, kv);

    gather_kernel<<<N_NODES, 256, 0, stream>>>(
        qsq, kv, offsets, sorted_src, sorted_fd);

    corr_kernel<<<(N_NODES + 63) / 64, 256, 0, stream>>>(webt, qsq);

    finalize_kernel<<<(N_NODES * CHAN + 255) / 256, 256, 0, stream>>>(
        qsq, nf, out);
}

// Round 6
// 147.653 us; speedup vs baseline: 5.5820x; 1.2225x over previous
//
#include <hip/hip_runtime.h>
#include <math.h>

#define N_NODES 10000
#define N_EDGES 100000
#define HIDDEN  128
#define NHEAD   4
#define CHAN    128
#define IN_DIM  137      // 128 + 6 + 3
#define KPAD    160      // padded K for MFMA
#define NCOLS   1904     // 512*3 + 128 + 240
#define NPAD    1920     // padded to 15*128
#define LATD    6
#define DISD    3

typedef __attribute__((ext_vector_type(8))) short short8v;
typedef __attribute__((ext_vector_type(4))) float float4v;

__device__ inline unsigned short f2bf(float f) {
    unsigned u = __float_as_uint(f);
    unsigned r = 0x7fffu + ((u >> 16) & 1u);
    return (unsigned short)((u + r) >> 16);
}
__device__ inline float bf2f(unsigned short u) {
    return __uint_as_float(((unsigned)u) << 16);
}

// ---------------- Kernel 0b: histogram of dst -------------------------------
__global__ __launch_bounds__(256) void hist_kernel(
    const int* __restrict__ eidx, int* __restrict__ hist)
{
    int e = blockIdx.x * 256 + threadIdx.x;
    if (e < N_EDGES) atomicAdd(&hist[eidx[N_EDGES + e]], 1);
}

// ---------------- Kernel 0c: exclusive scan (single block) ------------------
__global__ __launch_bounds__(1024) void scan_kernel(
    const int* __restrict__ hist, int* __restrict__ offsets, int* __restrict__ cursor)
{
    __shared__ int part[1024];
    const int t = threadIdx.x;
    const int base = t * 10;
    int loc[10];
    int s = 0;
    #pragma unroll
    for (int i = 0; i < 10; ++i) {
        int v = (base + i < N_NODES) ? hist[base + i] : 0;
        loc[i] = s; s += v;
    }
    part[t] = s;
    __syncthreads();
    for (int off = 1; off < 1024; off <<= 1) {
        int v = (t >= off) ? part[t - off] : 0;
        __syncthreads();
        part[t] += v;
        __syncthreads();
    }
    int pre = (t > 0) ? part[t - 1] : 0;
    #pragma unroll
    for (int i = 0; i < 10; ++i)
        if (base + i < N_NODES) {
            offsets[base + i] = pre + loc[i];
            cursor[base + i]  = pre + loc[i];
        }
    if (t == 1023) offsets[N_NODES] = part[1023];
}

// ---------------- Kernel 0d: scatter edges into dst-sorted order ------------
__global__ __launch_bounds__(256) void scatter_kernel(
    const int* __restrict__ eidx, const float* __restrict__ fdiff,
    int* __restrict__ cursor, int* __restrict__ sorted_src,
    float* __restrict__ sorted_fd)
{
    int e = blockIdx.x * 256 + threadIdx.x;
    if (e >= N_EDGES) return;
    int src = eidx[e];
    int dst = eidx[N_EDGES + e];
    int pos = atomicAdd(&cursor[dst], 1);
    sorted_src[pos] = src;
    sorted_fd[pos * 3 + 0] = fdiff[e * 3 + 0];
    sorted_fd[pos * 3 + 1] = fdiff[e * 3 + 1];
    sorted_fd[pos * 3 + 2] = fdiff[e * 3 + 2];
}

// ---------------- Kernel 1: LayerNorm + concat -> bf16 x [N][160]; zero hist -
__global__ __launch_bounds__(256) void prep_kernel(
    const float* __restrict__ nf, const float* __restrict__ frac,
    const float* __restrict__ lat, const int* __restrict__ n2g,
    const float* __restrict__ gamma, const float* __restrict__ beta,
    unsigned short* __restrict__ xb, int* __restrict__ hist)
{
    int wave = threadIdx.x >> 6;
    int lane = threadIdx.x & 63;
    int n = blockIdx.x * 4 + wave;
    if (n >= N_NODES) return;

    float v0 = nf[n * HIDDEN + lane];
    float v1 = nf[n * HIDDEN + 64 + lane];
    float s  = v0 + v1;
    float sq = v0 * v0 + v1 * v1;
    #pragma unroll
    for (int m = 1; m < 64; m <<= 1) {
        s  += __shfl_xor(s, m);
        sq += __shfl_xor(sq, m);
    }
    float mean = s * (1.0f / 128.0f);
    float var  = sq * (1.0f / 128.0f) - mean * mean;   // biased variance
    float inv  = rsqrtf(var + 1e-5f);

    xb[n * KPAD + lane]      = f2bf((v0 - mean) * inv * gamma[lane]      + beta[lane]);
    xb[n * KPAD + 64 + lane] = f2bf((v1 - mean) * inv * gamma[64 + lane] + beta[64 + lane]);
    if (lane < LATD) xb[n * KPAD + HIDDEN + lane]        = f2bf(lat[n2g[n] * LATD + lane]);
    if (lane < DISD) xb[n * KPAD + HIDDEN + LATD + lane] = f2bf(frac[n * DISD + lane]);
    if (lane >= 41)  xb[n * KPAD + 96 + lane] = 0;      // cols 137..159 zero-pad
    if (lane == 0)   hist[n] = 0;
}

// ---------------- Kernel 2: WallT bf16 (q,k,v,skip + fused Wqe) + Webt -------
__global__ __launch_bounds__(256) void weights_kernel(
    const float* __restrict__ Wq, const float* __restrict__ bq,
    const float* __restrict__ Wk, const float* __restrict__ bk,
    const float* __restrict__ Wv, const float* __restrict__ bv,
    const float* __restrict__ Wsk, const float* __restrict__ bsk,
    const float* __restrict__ We,
    unsigned short* __restrict__ wallT, float* __restrict__ bias_all,
    unsigned short* __restrict__ webt)
{
    int idx = blockIdx.x * 256 + threadIdx.x;   // < 1904*160 + 4*128*64
    if (idx < NCOLS * KPAD) {
        int n = idx / KPAD, k = idx % KPAD;
        if (n < 1664) {
            float val = 0.0f;
            if (k < IN_DIM) {
                if (n < 512)        val = Wq[(size_t)k * 512 + n];
                else if (n < 1024)  val = Wk[(size_t)k * 512 + (n - 512)];
                else if (n < 1536)  val = Wv[(size_t)k * 512 + (n - 1024)];
                else                val = Wsk[(size_t)k * 128 + (n - 1536)];
            }
            wallT[idx] = f2bf(val);
            if (k == 0) {
                float b;
                if (n < 512)        b = bq[n];
                else if (n < 1024)  b = bk[n - 512];
                else if (n < 1536)  b = bv[n - 1024];
                else                b = bsk[n - 1536];
                bias_all[n] = b;
            }
        } else {
            int hj = n - 1664;                      // 0..239
            int h = hj / 60, j = hj % 60;
            float s = 0.0f;
            if (k < IN_DIM) {
                #pragma unroll 4
                for (int c = 0; c < 128; ++c)
                    s += Wq[(size_t)k * 512 + h * 128 + c] * We[(size_t)j * 512 + h * 128 + c];
            }
            wallT[idx] = f2bf(s);
            if (k == KPAD - 1) {
                float b = 0.0f;
                #pragma unroll 4
                for (int c = 0; c < 128; ++c)
                    b += bq[h * 128 + c] * We[(size_t)j * 512 + h * 128 + c];
                bias_all[n] = b;
            }
        }
    } else {
        int g = idx - NCOLS * KPAD;                 // webt[h][c][j], 4*128*64
        int h = g >> 13, c = (g >> 6) & 127, j = g & 63;
        float v = (j < 60) ? We[(size_t)j * 512 + h * 128 + c] : 0.0f;
        webt[g] = f2bf(v);
    }
}

// ---------------- Kernel 3: MFMA GEMM xb[N,160] @ WallT^T --------------------
// A (64x160) staged in LDS; B fragments read DIRECTLY from global (wallT is
// [col][k] = exact fragment layout, L2-resident). q,k,v -> kvq bf16;
// skip,qe -> qsq f32.
__global__ __launch_bounds__(256) void mfma_gemm_kernel(
    const unsigned short* __restrict__ xb, const unsigned short* __restrict__ wallT,
    const float* __restrict__ bias_all,
    float* __restrict__ qsq, unsigned short* __restrict__ kvq)
{
    __shared__ __align__(16) unsigned short Alds[64 * 168];
    const int row0 = blockIdx.y * 64;
    const int col0 = blockIdx.x * 128;
    const int tid  = threadIdx.x;

    for (int i = tid; i < 64 * 20; i += 256) {       // A: 64 rows x 160 bf16
        int r = i / 20, c8 = (i % 20) * 8;
        uint4 v = make_uint4(0u, 0u, 0u, 0u);
        if (row0 + r < N_NODES)
            v = *reinterpret_cast<const uint4*>(&xb[(size_t)(row0 + r) * KPAD + c8]);
        *reinterpret_cast<uint4*>(&Alds[r * 168 + c8]) = v;
    }
    __syncthreads();

    const int l   = tid & 63;
    const int wid = tid >> 6;
    const int wr  = (wid >> 1) * 32;
    const int wc  = (wid & 1) * 64;
    const int lr  = l & 15;
    const int lk  = (l >> 4) * 8;

    float4v acc[2][4];
    #pragma unroll
    for (int tr = 0; tr < 2; ++tr)
        #pragma unroll
        for (int tc = 0; tc < 4; ++tc)
            acc[tr][tc] = (float4v){0.0f, 0.0f, 0.0f, 0.0f};

    #pragma unroll
    for (int ks = 0; ks < 5; ++ks) {
        short8v a[2], b[4];
        #pragma unroll
        for (int t = 0; t < 2; ++t)
            a[t] = *reinterpret_cast<const short8v*>(&Alds[(wr + t * 16 + lr) * 168 + ks * 32 + lk]);
        #pragma unroll
        for (int t = 0; t < 4; ++t)
            b[t] = *reinterpret_cast<const short8v*>(
                &wallT[(size_t)(col0 + wc + t * 16 + lr) * KPAD + ks * 32 + lk]);
        #pragma unroll
        for (int tr = 0; tr < 2; ++tr)
            #pragma unroll
            for (int tc = 0; tc < 4; ++tc)
                acc[tr][tc] = __builtin_amdgcn_mfma_f32_16x16x32_bf16(a[tr], b[tc], acc[tr][tc], 0, 0, 0);
    }

    #pragma unroll
    for (int tr = 0; tr < 2; ++tr) {
        #pragma unroll
        for (int tc = 0; tc < 4; ++tc) {
            const int col  = col0 + wc + tc * 16 + lr;
            const float bias = bias_all[col];
            #pragma unroll
            for (int j = 0; j < 4; ++j) {
                const int row = row0 + wr + tr * 16 + (l >> 4) * 4 + j;
                if (row < N_NODES) {
                    float val = acc[tr][tc][j] + bias;
                    if (col < 1536)                              // q,k,v -> bf16
                        kvq[(size_t)row * 1536 + col] = f2bf(val);
                    else if (col < NCOLS)                        // skip,qe -> f32
                        qsq[(size_t)row * 880 + (col - 1024)] = val;
                }
            }
        }
    }
}

// ---------------- Kernel 4: per-node gather; raw sums written back into qsq --
// Block = 1 node, wave = head, half-wave per edge, unroll 2.
// av (raw Σw*v) -> qsq cols [h*128, h*128+128); aggemb bf16 -> cols 640..767
// (256 ushorts, aliases qe after barrier); sumw -> col 768+h.
__global__ __launch_bounds__(256) void gather_kernel(
    float* __restrict__ qsq, const unsigned short* __restrict__ kvq,
    const int* __restrict__ offsets, const int* __restrict__ sorted_src,
    const float* __restrict__ sorted_fd)
{
    const int n    = blockIdx.x;
    const int h    = threadIdx.x >> 6;
    const int l    = threadIdx.x & 63;
    const int hl   = l & 31;
    const int half = l >> 5;
    const float TWO_PI = 6.283185307179586f;
    const float scale  = 0.08838834764831845f;   // 1/sqrt(128)

    float* row = qsq + (size_t)n * 880;
    const ushort4 qv = *reinterpret_cast<const ushort4*>(
        &kvq[(size_t)n * 1536 + h * 128 + 4 * hl]);
    const float q4x = bf2f(qv.x), q4y = bf2f(qv.y);
    const float q4z = bf2f(qv.z), q4w = bf2f(qv.w);
    const float qe_a = row[640 + h * 60 + hl];                 // j1 = hl (<60 always)
    const bool  v2ok = (hl < 28);                              // j2 = hl+32 < 60
    const float qe_b = v2ok ? row[640 + h * 60 + hl + 32] : 0.0f;

    // emb slot 1: j1 = hl; slot 2: j2 = hl+32 (always cos)
    const int   jj1  = (hl < 30) ? hl : hl - 30;
    const int   sd1  = jj1 / 10;
    const float fc1  = TWO_PI * (float)(jj1 % 10);
    const bool  sin1 = (hl < 30);
    const int   jj2  = hl + 2;
    const int   sd2  = v2ok ? (jj2 / 10) : 0;
    const float fc2  = v2ok ? TWO_PI * (float)(jj2 % 10) : 0.0f;

    float ax = 0.f, ay = 0.f, az = 0.f, aw = 0.f;
    float agg1 = 0.f, agg2 = 0.f, sumw = 0.f;
    const int e0 = offsets[n], e1 = offsets[n + 1];

    for (int base = e0; base < e1; base += 4) {
        const int eA = base + half;
        const int eB = base + half + 2;
        const bool okA = (eA < e1), okB = (eB < e1);
        const int iA = okA ? eA : e0;
        const int iB = okB ? eB : e0;
        const int srcA = sorted_src[iA];
        const int srcB = sorted_src[iB];
        const float fdA1 = sorted_fd[iA * 3 + sd1];
        const float fdA2 = sorted_fd[iA * 3 + sd2];
        const float fdB1 = sorted_fd[iB * 3 + sd1];
        const float fdB2 = sorted_fd[iB * 3 + sd2];
        const unsigned short* pA = &kvq[(size_t)srcA * 1536 + 512 + h * 128 + 4 * hl];
        const unsigned short* pB = &kvq[(size_t)srcB * 1536 + 512 + h * 128 + 4 * hl];
        const ushort4 kA = *reinterpret_cast<const ushort4*>(pA);
        const ushort4 vA = *reinterpret_cast<const ushort4*>(pA + 512);
        const ushort4 kB = *reinterpret_cast<const ushort4*>(pB);
        const ushort4 vB = *reinterpret_cast<const ushort4*>(pB + 512);

        const float eA1 = sin1 ? __sinf(fdA1 * fc1) : __cosf(fdA1 * fc1);
        const float eA2 = __cosf(fdA2 * fc2);
        const float eB1 = sin1 ? __sinf(fdB1 * fc1) : __cosf(fdB1 * fc1);
        const float eB2 = __cosf(fdB2 * fc2);

        float pAs = q4x * bf2f(kA.x) + q4y * bf2f(kA.y)
                  + q4z * bf2f(kA.z) + q4w * bf2f(kA.w)
                  + eA1 * qe_a + eA2 * qe_b;
        float pBs = q4x * bf2f(kB.x) + q4y * bf2f(kB.y)
                  + q4z * bf2f(kB.z) + q4w * bf2f(kB.w)
                  + eB1 * qe_a + eB2 * qe_b;
        #pragma unroll
        for (int m = 1; m <= 16; m <<= 1) {
            pAs += __shfl_xor(pAs, m);
            pBs += __shfl_xor(pBs, m);
        }
        const float wA = okA ? __expf(pAs * scale) : 0.0f;
        const float wB = okB ? __expf(pBs * scale) : 0.0f;
        sumw += wA + wB;
        ax += wA * bf2f(vA.x) + wB * bf2f(vB.x);
        ay += wA * bf2f(vA.y) + wB * bf2f(vB.y);
        az += wA * bf2f(vA.z) + wB * bf2f(vB.z);
        aw += wA * bf2f(vA.w) + wB * bf2f(vB.w);
        agg1 += wA * eA1 + wB * eB1;
        if (v2ok) agg2 += wA * eA2 + wB * eB2;
    }

    // combine the two halves
    sumw += __shfl_xor(sumw, 32);
    ax += __shfl_xor(ax, 32);  ay += __shfl_xor(ay, 32);
    az += __shfl_xor(az, 32);  aw += __shfl_xor(aw, 32);
    agg1 += __shfl_xor(agg1, 32);
    agg2 += __shfl_xor(agg2, 32);

    // barrier: all waves' qe reads must complete before aliased writes
    __syncthreads();

    if (half == 0) {
        float4 r;
        r.x = ax; r.y = ay; r.z = az; r.w = aw;
        *reinterpret_cast<float4*>(&row[h * 128 + 4 * hl]) = r;   // raw Σw*v
        unsigned short* us = (unsigned short*)(row + 640);        // aggemb bf16
        us[h * 64 + hl]      = f2bf(agg1);                        // j = hl
        us[h * 64 + 32 + hl] = f2bf(agg2);                        // j = hl+32 (0 pad j>=60)
        if (hl == 0) row[768 + h] = sumw;
    }
}

// ---------------- Kernel 5: corr MFMA — av += aggemb @ Webt ------------------
// Block = 32 nodes, 4 waves (wave h = head h). A: aggemb [32][256] bf16 from
// qsq cols 640..; B direct from global webt[h][128][64] (L2-resident, 64 KB).
__global__ __launch_bounds__(256) void corr_kernel(
    const unsigned short* __restrict__ webt, float* __restrict__ qsq)
{
    __shared__ __align__(16) unsigned short Alds[32 * 264];
    const int node0 = blockIdx.x * 32;
    const int tid = threadIdx.x;

    for (int i = tid; i < 32 * 32; i += 256) {       // A: 1024 uint4
        int r = i >> 5, c8 = (i & 31) * 8;
        uint4 v = make_uint4(0u, 0u, 0u, 0u);
        if (node0 + r < N_NODES)
            v = *reinterpret_cast<const uint4*>(
                (const unsigned short*)(qsq + (size_t)(node0 + r) * 880 + 640) + c8);
        *reinterpret_cast<uint4*>(&Alds[r * 264 + c8]) = v;
    }
    __syncthreads();

    const int l  = tid & 63;
    const int h  = tid >> 6;
    const int lr = l & 15;
    const int lk = (l >> 4) * 8;

    float4v acc[2][8];
    #pragma unroll
    for (int m = 0; m < 2; ++m)
        #pragma unroll
        for (int nn = 0; nn < 8; ++nn)
            acc[m][nn] = (float4v){0.0f, 0.0f, 0.0f, 0.0f};

    #pragma unroll
    for (int ks = 0; ks < 2; ++ks) {
        short8v a[2], b[8];
        #pragma unroll
        for (int m = 0; m < 2; ++m)
            a[m] = *reinterpret_cast<const short8v*>(
                &Alds[(m * 16 + lr) * 264 + h * 64 + ks * 32 + lk]);
        #pragma unroll
        for (int nn = 0; nn < 8; ++nn)
            b[nn] = *reinterpret_cast<const short8v*>(
                &webt[(size_t)(h * 128 + nn * 16 + lr) * 64 + ks * 32 + lk]);
        #pragma unroll
        for (int m = 0; m < 2; ++m)
            #pragma unroll
            for (int nn = 0; nn < 8; ++nn)
                acc[m][nn] = __builtin_amdgcn_mfma_f32_16x16x32_bf16(a[m], b[nn], acc[m][nn], 0, 0, 0);
    }

    #pragma unroll
    for (int m = 0; m < 2; ++m) {
        #pragma unroll
        for (int nn = 0; nn < 8; ++nn) {
            const int col = h * 128 + nn * 16 + lr;
            #pragma unroll
            for (int j = 0; j < 4; ++j) {
                const int rowi = node0 + m * 16 + (l >> 4) * 4 + j;
                if (rowi < N_NODES) {
                    float* p = &qsq[(size_t)rowi * 880 + col];
                    *p += acc[m][nn][j];
                }
            }
        }
    }
}

// ---------------- Kernel 6: finalize ----------------------------------------
__global__ __launch_bounds__(256) void finalize_kernel(
    const float* __restrict__ qsq, const float* __restrict__ nf,
    float* __restrict__ out)
{
    int idx = blockIdx.x * 256 + threadIdx.x;
    if (idx >= N_NODES * CHAN) return;
    int n = idx >> 7, c = idx & 127;
    const float* row = qsq + (size_t)n * 880;
    float z = 0.0f;
    #pragma unroll
    for (int h = 0; h < NHEAD; ++h)
        z += row[h * 128 + c] / (row[768 + h] + 1e-16f);
    z = 0.25f * z + row[512 + c];                   // head mean + skip
    float si = z / (1.0f + __expf(-z));             // silu
    out[idx] = nf[idx] + si;
}

// ---------------- launcher ---------------------------------------------------
extern "C" void kernel_launch(void* const* d_in, const int* in_sizes, int n_in,
                              void* d_out, int out_size, void* d_ws, size_t ws_size,
                              hipStream_t stream)
{
    const float* nf    = (const float*)d_in[0];
    const float* frac  = (const float*)d_in[1];
    const float* lat   = (const float*)d_in[2];
    const int*   eidx  = (const int*)  d_in[3];
    const int*   n2g   = (const int*)  d_in[4];
    const float* fdiff = (const float*)d_in[5];
    const float* gamma = (const float*)d_in[6];
    const float* beta  = (const float*)d_in[7];
    const float* Wq    = (const float*)d_in[8];
    const float* bq    = (const float*)d_in[9];
    const float* Wk    = (const float*)d_in[10];
    const float* bk    = (const float*)d_in[11];
    const float* Wv    = (const float*)d_in[12];
    const float* bv    = (const float*)d_in[13];
    const float* We    = (const float*)d_in[14];
    const float* Wsk   = (const float*)d_in[15];
    const float* bsk   = (const float*)d_in[16];
    float* out = (float*)d_out;

    // workspace layout
    float* qsq       = (float*)d_ws;                               // N*880
    float* bias_all  = qsq + (size_t)N_NODES * 880;                // 1920
    float* sorted_fd = bias_all + NPAD;                            // E*3
    unsigned short* xb    = (unsigned short*)(sorted_fd + (size_t)N_EDGES * 3); // N*160
    unsigned short* wallT = xb + (size_t)N_NODES * KPAD;           // 1920*160
    unsigned short* webt  = wallT + (size_t)NPAD * KPAD;           // 4*128*64
    unsigned short* kvq   = webt + 4 * 128 * 64;                   // N*1536
    int* hist       = (int*)(kvq + (size_t)N_NODES * 1536);        // N
    int* offsets    = hist + N_NODES;                              // N+1
    int* cursor     = offsets + N_NODES + 1;                       // N
    int* sorted_src = cursor + N_NODES;                            // E

    prep_kernel<<<(N_NODES + 3) / 4, 256, 0, stream>>>(
        nf, frac, lat, n2g, gamma, beta, xb, hist);
    hist_kernel<<<(N_EDGES + 255) / 256, 256, 0, stream>>>(eidx, hist);
    scan_kernel<<<1, 1024, 0, stream>>>(hist, offsets, cursor);
    scatter_kernel<<<(N_EDGES + 255) / 256, 256, 0, stream>>>(
        eidx, fdiff, cursor, sorted_src, sorted_fd);

    weights_kernel<<<(NCOLS * KPAD + 4 * 128 * 64) / 256, 256, 0, stream>>>(
        Wq, bq, Wk, bk, Wv, bv, Wsk, bsk, We, wallT, bias_all, webt);

    dim3 ggrid(NPAD / 128, (N_NODES + 63) / 64);
    mfma_gemm_kernel<<<ggrid, 256, 0, stream>>>(xb, wallT, bias_all, qsq, kvq);

    gather_kernel<<<N_NODES, 256, 0, stream>>>(
        qsq, kvq, offsets, sorted_src, sorted_fd);

    corr_kernel<<<(N_NODES + 31) / 32, 256, 0, stream>>>(webt, qsq);

    finalize_kernel<<<(N_NODES * CHAN + 255) / 256, 256, 0, stream>>>(
        qsq, nf, out);
}